// Round 14
// baseline (577.151 us; speedup 1.0000x reference)
//
#include <hip/hip_runtime.h>
#include <math.h>

#define NDIM 64
typedef float f32x2 __attribute__((ext_vector_type(2)));

#define MEMFENCE() asm volatile("" ::: "memory")

// Broadcast lane `lane`'s value to all lanes (uniform / SGPR).
__device__ __forceinline__ float rl(float v, int lane) {
    return __uint_as_float((unsigned)__builtin_amdgcn_readlane(__float_as_uint(v), lane));
}

// DPP add step with compile-time control/row mask.
template<int CTRL, int ROW_MASK>
__device__ __forceinline__ float dpp_add(float x) {
    int m = __builtin_amdgcn_update_dpp(0, __float_as_int(x), CTRL, ROW_MASK, 0xf, true);
    return x + __int_as_float(m);
}
// Full-wave64 sum via DPP; total lands in lane 63, broadcast via readlane.
__device__ __forceinline__ float wave_sum(float x) {
    x = dpp_add<0x111, 0xf>(x);   // row_shr:1
    x = dpp_add<0x112, 0xf>(x);   // row_shr:2
    x = dpp_add<0x114, 0xf>(x);   // row_shr:4
    x = dpp_add<0x118, 0xf>(x);   // row_shr:8
    x = dpp_add<0x142, 0xa>(x);   // row_bcast:15 -> rows 1,3
    x = dpp_add<0x143, 0xc>(x);   // row_bcast:31 -> row 3
    return rl(x, 63);
}
__device__ __forceinline__ float wave_min(float v) {
    #pragma unroll
    for (int off = 1; off < 64; off <<= 1) v = fminf(v, __shfl_xor(v, off, 64));
    return v;
}
__device__ __forceinline__ float wave_max(float v) {
    #pragma unroll
    for (int off = 1; off < 64; off <<= 1) v = fmaxf(v, __shfl_xor(v, off, 64));
    return v;
}

// Build symmetrized row t into r2 (32 x f32x2) using readlane broadcasts.
__device__ __forceinline__ void build_rows(f32x2 (&r2)[32], const float* ws,
                                           float xi, float yi, int t) {
    const float4* Sa4 = (const float4*)(ws + t * NDIM);
    const float4* Bh4 = (const float4*)(ws + 4096 + t * NDIM);
    const float4* Bt4 = (const float4*)(ws + 8192 + t * NDIM);
    const float4* Ch4 = (const float4*)(ws + 12288 + t * NDIM);
    const float4* Ct4 = (const float4*)(ws + 16384 + t * NDIM);
    #pragma unroll
    for (int q = 0; q < 16; ++q) {
        float4 sa = Sa4[q], bh = Bh4[q], bt = Bt4[q], ch = Ch4[q], ct = Ct4[q];
        float x0 = rl(xi, 4 * q),     y0 = rl(yi, 4 * q);
        float x1 = rl(xi, 4 * q + 1), y1 = rl(yi, 4 * q + 1);
        float x2 = rl(xi, 4 * q + 2), y2 = rl(yi, 4 * q + 2);
        float x3 = rl(xi, 4 * q + 3), y3 = rl(yi, 4 * q + 3);
        float e0 = fmaf(bh.x, x0, fmaf(bt.x, xi, fmaf(ch.x, y0, fmaf(ct.x, yi, sa.x))));
        float e1 = fmaf(bh.y, x1, fmaf(bt.y, xi, fmaf(ch.y, y1, fmaf(ct.y, yi, sa.y))));
        float e2 = fmaf(bh.z, x2, fmaf(bt.z, xi, fmaf(ch.z, y2, fmaf(ct.z, yi, sa.z))));
        float e3 = fmaf(bh.w, x3, fmaf(bt.w, xi, fmaf(ch.w, y3, fmaf(ct.w, yi, sa.w))));
        r2[2 * q].x = e0;     r2[2 * q].y = e1;
        r2[2 * q + 1].x = e2; r2[2 * q + 1].y = e3;
    }
}

// Shared tail: Gershgorin bounds + 64-way Sturm multisection, write out.
__device__ __forceinline__ void sturm_out(float dval, float e2val, int idx,
                                          int t, int b, float* out) {
    float eabs = sqrtf(e2val);
    float eprev = __shfl_up(eabs, 1, 64);
    eprev = (t == 0) ? 0.0f : eprev;
    float rad = eabs + eprev;
    float lo = wave_min(dval - rad);
    float hi = wave_max(dval + rad);
    float pad = 1e-3f + 1e-5f * fmaxf(fabsf(lo), fabsf(hi));
    lo -= pad;
    hi += pad;

    #pragma unroll 1
    for (int it = 0; it < 2; ++it) {
        float wdt = (hi - lo) * (1.0f / 65.0f);
        float s = lo + wdt * (float)(t + 1);
        float q = rl(dval, 0) - s;
        q = (fabsf(q) < 1e-12f) ? -1e-12f : q;
        int cnt = (q < 0.0f) ? 1 : 0;
        #pragma unroll
        for (int i = 1; i < NDIM; ++i) {
            q = rl(dval, i) - s - rl(e2val, i - 1) * __builtin_amdgcn_rcpf(q);
            q = (fabsf(q) < 1e-12f) ? -1e-12f : q;
            cnt += (q < 0.0f) ? 1 : 0;
        }
        unsigned long long m = __ballot(cnt <= idx);
        int p = (int)__popcll(m);
        float nlo = lo + wdt * (float)p;
        float nhi = lo + wdt * (float)(p + 1);
        lo = nlo;
        hi = (p >= 64) ? hi : nhi;
    }
    if (t == 0) out[b] = 0.5f * (lo + hi);
}

// One-time prep: Sa = 0.5(A+A^T), Bh = 0.5B, Bt = 0.5B^T, Ch = 0.5C, Ct = 0.5C^T.
__global__ __launch_bounds__(64)
void prep_kernel(const float* __restrict__ A, const float* __restrict__ B,
                 const float* __restrict__ C, float* __restrict__ ws) {
    const int t = threadIdx.x;
    float* Sa = ws;
    float* Bh = ws + 4096;
    float* Bt = ws + 8192;
    float* Ch = ws + 12288;
    float* Ct = ws + 16384;
    for (int j = 0; j < NDIM; ++j) {
        Sa[t * NDIM + j] = 0.5f * (A[t * NDIM + j] + A[j * NDIM + t]);
        Bh[t * NDIM + j] = 0.5f * B[t * NDIM + j];
        Bt[t * NDIM + j] = 0.5f * B[j * NDIM + t];
        Ch[t * NDIM + j] = 0.5f * C[t * NDIM + j];
        Ct[t * NDIM + j] = 0.5f * C[j * NDIM + t];
    }
}

// ===== Dual-matrix Lanczos: extreme indices (idx==0 or idx==63). Two
// independent Lanczos chains per wave, interleaved for ILP. Rows constant;
// merged reductions: alpha = sum(q*w), sww = sum(w*w) run as independent
// DPP chains; beta^2 = sww - alpha^2 (w perp q up to alpha-component). =====
__global__ __launch_bounds__(256, 1)
void lanczos_kernel(const float* __restrict__ x, const float* __restrict__ y,
                    const float* __restrict__ ws, const int* __restrict__ idxp,
                    float* __restrict__ out, int batch) {
    int idx = idxp[0];
    idx = idx < 0 ? 0 : (idx > NDIM - 1 ? NDIM - 1 : idx);
    if (idx != 0 && idx != NDIM - 1) return;   // interior: householder kernel

    const int t = threadIdx.x & 63;
    const int wv = threadIdx.x >> 6;
    const int bA = blockIdx.x * 8 + wv * 2;
    const int bB = bA + 1;
    if (bA >= batch) return;
    const bool hasB = (bB < batch);

    __shared__ float4 qbs[4][2][16];
    float4* qbA = qbs[wv][0];
    float4* qbB = qbs[wv][1];
    float* qpA_ = (float*)qbA;
    float* qpB_ = (float*)qbB;

    const float xiA = x[bA * NDIM + t];
    const float yiA = y[bA * NDIM + t];
    const float xiB = hasB ? x[bB * NDIM + t] : 0.0f;
    const float yiB = hasB ? y[bB * NDIM + t] : 0.0f;

    f32x2 rA[32], rB[32];
    build_rows(rA, ws, xiA, yiA, t);
    build_rows(rB, ws, xiB, yiB, t);

    // Lanczos: q0 = e_0. T diag alpha_k -> lane k, offdiag beta_{k+1}^2 -> lane k.
    float qA = (t == 0) ? 1.0f : 0.0f;
    float qB = qA;
    float qpA = 0.0f, qpB = 0.0f;
    float bprevA = 0.0f, bprevB = 0.0f;
    float dA = 0.0f, dB = 0.0f, e2A = 0.0f, e2B = 0.0f;
    #pragma unroll 1
    for (int k = 0; k < NDIM; ++k) {
        qpA_[t] = qA;
        qpB_[t] = qB;
        MEMFENCE();
        f32x2 aA0 = {0.0f, 0.0f}, aA1 = {0.0f, 0.0f};
        f32x2 aB0 = {0.0f, 0.0f}, aB1 = {0.0f, 0.0f};
        #pragma unroll
        for (int m = 0; m < 16; ++m) {
            float4 qa = qbA[m];
            float4 qb = qbB[m];
            f32x2 qa01; qa01.x = qa.x; qa01.y = qa.y;
            f32x2 qa23; qa23.x = qa.z; qa23.y = qa.w;
            f32x2 qb01; qb01.x = qb.x; qb01.y = qb.y;
            f32x2 qb23; qb23.x = qb.z; qb23.y = qb.w;
            aA0 = __builtin_elementwise_fma(rA[2 * m],     qa01, aA0);
            aB0 = __builtin_elementwise_fma(rB[2 * m],     qb01, aB0);
            aA1 = __builtin_elementwise_fma(rA[2 * m + 1], qa23, aA1);
            aB1 = __builtin_elementwise_fma(rB[2 * m + 1], qb23, aB1);
        }
        float wA = (aA0.x + aA0.y) + (aA1.x + aA1.y);
        float wB = (aB0.x + aB0.y) + (aB1.x + aB1.y);
        wA = fmaf(-bprevA, qpA, wA);
        wB = fmaf(-bprevB, qpB, wB);
        // merged reductions: 4 independent DPP chains interleave
        float alphaA = wave_sum(qA * wA);
        float alphaB = wave_sum(qB * wB);
        float swwA = wave_sum(wA * wA);
        float swwB = wave_sum(wB * wB);
        float b2A = fmaxf(swwA - alphaA * alphaA, 0.0f);
        float b2B = fmaxf(swwB - alphaB * alphaB, 0.0f);
        bool cap = (t == k);
        dA = cap ? alphaA : dA;
        dB = cap ? alphaB : dB;
        e2A = cap ? b2A : e2A;
        e2B = cap ? b2B : e2B;
        float wnA = fmaf(-alphaA, qA, wA);
        float wnB = fmaf(-alphaB, qB, wB);
        float biA = (b2A > 1e-20f) ? rsqrtf(b2A) : 0.0f;
        float biB = (b2B > 1e-20f) ? rsqrtf(b2B) : 0.0f;
        qpA = qA; qpB = qB;
        qA = wnA * biA;
        qB = wnB * biB;
        bprevA = b2A * biA;                 // sqrt(b2)
        bprevB = b2B * biB;
    }

    sturm_out(dA, e2A, idx, t, bA, out);
    if (hasB) sturm_out(dB, e2B, idx, t, bB, out);
}

// ===== Householder path: interior indices (exact-count Sturm needs a
// ghost-free tridiagonal). Verified R12 structure. =====
template<int K0, int K1>
__device__ __forceinline__ void tri_chunk(f32x2 (&r2)[32], float& colreg,
                                          float& dval, float& e2val, const int t) {
    #pragma unroll 1
    for (int k = K0; k < K1; ++k) {
        float akt = (t > k) ? colreg : 0.0f;
        float s2 = wave_sum(akt * akt);
        float a1 = rl(akt, k + 1);
        float sigma = sqrtf(s2);
        float alpha = (a1 >= 0.0f) ? -sigma : sigma;
        e2val = (t == k) ? s2 : e2val;
        float vt = akt - ((t == k + 1) ? alpha : 0.0f);
        float vtv = 2.0f * (s2 - alpha * a1);
        float beta = (vtv > 1e-30f) ? 2.0f * __builtin_amdgcn_rcpf(vtv) : 0.0f;

        float pre_col = colreg;
        #pragma unroll
        for (int j = K0 + 1; j <= K1; ++j)
            if (j == k + 1) pre_col = (j & 1) ? r2[j >> 1].y : r2[j >> 1].x;

        f32x2 acc0 = {0.0f, 0.0f}, acc1 = {0.0f, 0.0f};
        #pragma unroll
        for (int p = K0 / 2; p < 32; ++p) {
            f32x2 a;
            a.x = rl(akt, 2 * p);
            a.y = rl(akt, 2 * p + 1);
            if (p & 1) acc1 = __builtin_elementwise_fma(r2[p], a, acc1);
            else       acc0 = __builtin_elementwise_fma(r2[p], a, acc0);
        }
        float ut = (acc0.x + acc0.y) + (acc1.x + acc1.y) - alpha * pre_col;
        float vtu = wave_sum(vt * ut);
        float c  = 0.5f * beta * beta * vtu;
        float p1 = vt * beta;
        float p2 = (t > k) ? (beta * ut - 2.0f * c * vt) : 0.0f;
        float uk1 = rl(ut, k + 1);
        float ncol = pre_col - p1 * uk1 - p2 * a1 + alpha * p2;

        f32x2 np1; np1.x = -p1; np1.y = -p1;
        f32x2 np2; np2.x = -p2; np2.y = -p2;
        #pragma unroll
        for (int p = K0 / 2; p < 32; ++p) {
            f32x2 u, a;
            u.x = rl(ut, 2 * p);
            u.y = rl(ut, 2 * p + 1);
            a.x = rl(akt, 2 * p);
            a.y = rl(akt, 2 * p + 1);
            r2[p] = __builtin_elementwise_fma(np1, u,
                    __builtin_elementwise_fma(np2, a, r2[p]));
        }
        #pragma unroll
        for (int j = K0 + 1; j <= K1; ++j) {
            if (j == k + 1) {
                if (j & 1) r2[j >> 1].y = ncol; else r2[j >> 1].x = ncol;
            }
        }
        colreg = ncol;
        dval = (t == k + 1) ? ncol : dval;
    }
}

__global__ __launch_bounds__(256, 1)
void householder_kernel(const float* __restrict__ x, const float* __restrict__ y,
                        const float* __restrict__ ws, const int* __restrict__ idxp,
                        float* __restrict__ out, int batch) {
    int idx = idxp[0];
    idx = idx < 0 ? 0 : (idx > NDIM - 1 ? NDIM - 1 : idx);
    if (idx == 0 || idx == NDIM - 1) return;   // handled by lanczos kernel

    const int t = threadIdx.x & 63;
    const int b = blockIdx.x * 4 + (threadIdx.x >> 6);
    if (b >= batch) return;

    const float xi = x[b * NDIM + t];
    const float yi = y[b * NDIM + t];
    f32x2 r2[32];
    build_rows(r2, ws, xi, yi, t);

    float colreg = r2[0].x;
    float dval = (t == 0) ? r2[0].x : 0.0f;
    float e2val = 0.0f;
    tri_chunk< 0,  8>(r2, colreg, dval, e2val, t);
    tri_chunk< 8, 16>(r2, colreg, dval, e2val, t);
    tri_chunk<16, 24>(r2, colreg, dval, e2val, t);
    tri_chunk<24, 32>(r2, colreg, dval, e2val, t);
    tri_chunk<32, 40>(r2, colreg, dval, e2val, t);
    tri_chunk<40, 48>(r2, colreg, dval, e2val, t);
    tri_chunk<48, 56>(r2, colreg, dval, e2val, t);
    tri_chunk<56, 62>(r2, colreg, dval, e2val, t);

    float e62 = rl(colreg, 63);
    e2val = (t == 62) ? e62 * e62 : e2val;
    dval = (t == 63) ? r2[31].y : dval;

    sturm_out(dval, e2val, idx, t, b, out);
}

extern "C" void kernel_launch(void* const* d_in, const int* in_sizes, int n_in,
                              void* d_out, int out_size, void* d_ws, size_t ws_size,
                              hipStream_t stream) {
    const float* x = (const float*)d_in[0];
    const float* y = (const float*)d_in[1];
    const float* A = (const float*)d_in[2];
    const float* B = (const float*)d_in[3];
    const float* C = (const float*)d_in[4];
    const int* idxp = (const int*)d_in[5];
    float* out = (float*)d_out;
    float* ws = (float*)d_ws;
    int batch = in_sizes[0] / NDIM;

    hipLaunchKernelGGL(prep_kernel, dim3(1), dim3(64), 0, stream, A, B, C, ws);
    hipLaunchKernelGGL(lanczos_kernel, dim3((batch + 7) / 8), dim3(256), 0, stream,
                       x, y, ws, idxp, out, batch);
    hipLaunchKernelGGL(householder_kernel, dim3((batch + 3) / 4), dim3(256), 0, stream,
                       x, y, ws, idxp, out, batch);
}

// Round 15
// 472.141 us; speedup vs baseline: 1.2224x; 1.2224x over previous
//
#include <hip/hip_runtime.h>
#include <math.h>

#define NDIM 64
typedef float f32x2 __attribute__((ext_vector_type(2)));

#define MEMFENCE() asm volatile("" ::: "memory")

// Broadcast lane `lane`'s value to all lanes (uniform / SGPR).
__device__ __forceinline__ float rl(float v, int lane) {
    return __uint_as_float((unsigned)__builtin_amdgcn_readlane(__float_as_uint(v), lane));
}

// DPP add step with compile-time control/row mask.
template<int CTRL, int ROW_MASK>
__device__ __forceinline__ float dpp_add(float x) {
    int m = __builtin_amdgcn_update_dpp(0, __float_as_int(x), CTRL, ROW_MASK, 0xf, true);
    return x + __int_as_float(m);
}
// Full-wave64 sum via DPP; total lands in lane 63, broadcast via readlane.
__device__ __forceinline__ float wave_sum(float x) {
    x = dpp_add<0x111, 0xf>(x);   // row_shr:1
    x = dpp_add<0x112, 0xf>(x);   // row_shr:2
    x = dpp_add<0x114, 0xf>(x);   // row_shr:4
    x = dpp_add<0x118, 0xf>(x);   // row_shr:8
    x = dpp_add<0x142, 0xa>(x);   // row_bcast:15 -> rows 1,3
    x = dpp_add<0x143, 0xc>(x);   // row_bcast:31 -> row 3
    return rl(x, 63);
}
__device__ __forceinline__ float wave_min(float v) {
    #pragma unroll
    for (int off = 1; off < 64; off <<= 1) v = fminf(v, __shfl_xor(v, off, 64));
    return v;
}
__device__ __forceinline__ float wave_max(float v) {
    #pragma unroll
    for (int off = 1; off < 64; off <<= 1) v = fmaxf(v, __shfl_xor(v, off, 64));
    return v;
}

// Build symmetrized row t into r2 (32 x f32x2) using readlane broadcasts.
__device__ __forceinline__ void build_rows(f32x2 (&r2)[32], const float* ws,
                                           float xi, float yi, int t) {
    const float4* Sa4 = (const float4*)(ws + t * NDIM);
    const float4* Bh4 = (const float4*)(ws + 4096 + t * NDIM);
    const float4* Bt4 = (const float4*)(ws + 8192 + t * NDIM);
    const float4* Ch4 = (const float4*)(ws + 12288 + t * NDIM);
    const float4* Ct4 = (const float4*)(ws + 16384 + t * NDIM);
    #pragma unroll
    for (int q = 0; q < 16; ++q) {
        float4 sa = Sa4[q], bh = Bh4[q], bt = Bt4[q], ch = Ch4[q], ct = Ct4[q];
        float x0 = rl(xi, 4 * q),     y0 = rl(yi, 4 * q);
        float x1 = rl(xi, 4 * q + 1), y1 = rl(yi, 4 * q + 1);
        float x2 = rl(xi, 4 * q + 2), y2 = rl(yi, 4 * q + 2);
        float x3 = rl(xi, 4 * q + 3), y3 = rl(yi, 4 * q + 3);
        float e0 = fmaf(bh.x, x0, fmaf(bt.x, xi, fmaf(ch.x, y0, fmaf(ct.x, yi, sa.x))));
        float e1 = fmaf(bh.y, x1, fmaf(bt.y, xi, fmaf(ch.y, y1, fmaf(ct.y, yi, sa.y))));
        float e2 = fmaf(bh.z, x2, fmaf(bt.z, xi, fmaf(ch.z, y2, fmaf(ct.z, yi, sa.z))));
        float e3 = fmaf(bh.w, x3, fmaf(bt.w, xi, fmaf(ch.w, y3, fmaf(ct.w, yi, sa.w))));
        r2[2 * q].x = e0;     r2[2 * q].y = e1;
        r2[2 * q + 1].x = e2; r2[2 * q + 1].y = e3;
    }
}

// Shared tail: Gershgorin bounds + 64-way Sturm multisection, write out.
__device__ __forceinline__ void sturm_out(float dval, float e2val, int idx,
                                          int t, int b, float* out) {
    float eabs = sqrtf(e2val);
    float eprev = __shfl_up(eabs, 1, 64);
    eprev = (t == 0) ? 0.0f : eprev;
    float rad = eabs + eprev;
    float lo = wave_min(dval - rad);
    float hi = wave_max(dval + rad);
    float pad = 1e-3f + 1e-5f * fmaxf(fabsf(lo), fabsf(hi));
    lo -= pad;
    hi += pad;

    #pragma unroll 1
    for (int it = 0; it < 2; ++it) {
        float wdt = (hi - lo) * (1.0f / 65.0f);
        float s = lo + wdt * (float)(t + 1);
        float q = rl(dval, 0) - s;
        q = (fabsf(q) < 1e-12f) ? -1e-12f : q;
        int cnt = (q < 0.0f) ? 1 : 0;
        #pragma unroll
        for (int i = 1; i < NDIM; ++i) {
            q = rl(dval, i) - s - rl(e2val, i - 1) * __builtin_amdgcn_rcpf(q);
            q = (fabsf(q) < 1e-12f) ? -1e-12f : q;
            cnt += (q < 0.0f) ? 1 : 0;
        }
        unsigned long long m = __ballot(cnt <= idx);
        int p = (int)__popcll(m);
        float nlo = lo + wdt * (float)p;
        float nhi = lo + wdt * (float)(p + 1);
        lo = nlo;
        hi = (p >= 64) ? hi : nhi;
    }
    if (t == 0) out[b] = 0.5f * (lo + hi);
}

// One-time prep: Sa = 0.5(A+A^T), Bh = 0.5B, Bt = 0.5B^T, Ch = 0.5C, Ct = 0.5C^T.
__global__ __launch_bounds__(64)
void prep_kernel(const float* __restrict__ A, const float* __restrict__ B,
                 const float* __restrict__ C, float* __restrict__ ws) {
    const int t = threadIdx.x;
    float* Sa = ws;
    float* Bh = ws + 4096;
    float* Bt = ws + 8192;
    float* Ch = ws + 12288;
    float* Ct = ws + 16384;
    for (int j = 0; j < NDIM; ++j) {
        Sa[t * NDIM + j] = 0.5f * (A[t * NDIM + j] + A[j * NDIM + t]);
        Bh[t * NDIM + j] = 0.5f * B[t * NDIM + j];
        Bt[t * NDIM + j] = 0.5f * B[j * NDIM + t];
        Ch[t * NDIM + j] = 0.5f * C[t * NDIM + j];
        Ct[t * NDIM + j] = 0.5f * C[j * NDIM + t];
    }
}

// ===== Single-matrix Lanczos, extreme indices (idx==0 or idx==63).
// Rows constant; per step: LDS-broadcast matvec (4 acc chains), merged
// independent reductions alpha/sww (beta^2 = sww - alpha^2), q written to
// LDS immediately after normalization, captures in the write shadow.
// Last step peeled (alpha only). =====
__global__ __launch_bounds__(256, 4)
void lanczos_kernel(const float* __restrict__ x, const float* __restrict__ y,
                    const float* __restrict__ ws, const int* __restrict__ idxp,
                    float* __restrict__ out, int batch) {
    int idx = idxp[0];
    idx = idx < 0 ? 0 : (idx > NDIM - 1 ? NDIM - 1 : idx);
    if (idx != 0 && idx != NDIM - 1) return;   // interior: householder kernel

    const int t = threadIdx.x & 63;
    const int wv = threadIdx.x >> 6;
    const int b = blockIdx.x * 4 + wv;
    if (b >= batch) return;

    __shared__ float4 qbs[4][16];
    float4* qb = qbs[wv];
    float* qbp = (float*)qb;

    const float xi = x[b * NDIM + t];
    const float yi = y[b * NDIM + t];
    f32x2 r2[32];
    build_rows(r2, ws, xi, yi, t);

    // Lanczos: q0 = e_0. T diag alpha_k -> lane k, offdiag beta_{k+1}^2 -> lane k.
    float q = (t == 0) ? 1.0f : 0.0f;
    qbp[t] = q;
    MEMFENCE();
    float qp = 0.0f, bprev = 0.0f;
    float dval = 0.0f, e2val = 0.0f;
    #pragma unroll 1
    for (int k = 0; k < NDIM - 1; ++k) {
        // matvec: 4 independent 8-deep pk-FMA chains
        f32x2 a0 = {0.0f, 0.0f}, a1 = {0.0f, 0.0f};
        f32x2 a2 = {0.0f, 0.0f}, a3 = {0.0f, 0.0f};
        #pragma unroll
        for (int m = 0; m < 16; m += 2) {
            float4 q0 = qb[m];
            float4 q1 = qb[m + 1];
            f32x2 u01; u01.x = q0.x; u01.y = q0.y;
            f32x2 u23; u23.x = q0.z; u23.y = q0.w;
            f32x2 v01; v01.x = q1.x; v01.y = q1.y;
            f32x2 v23; v23.x = q1.z; v23.y = q1.w;
            a0 = __builtin_elementwise_fma(r2[2 * m],     u01, a0);
            a1 = __builtin_elementwise_fma(r2[2 * m + 1], u23, a1);
            a2 = __builtin_elementwise_fma(r2[2 * m + 2], v01, a2);
            a3 = __builtin_elementwise_fma(r2[2 * m + 3], v23, a3);
        }
        float w = ((a0.x + a0.y) + (a1.x + a1.y)) + ((a2.x + a2.y) + (a3.x + a3.y));
        w = fmaf(-bprev, qp, w);
        // merged independent reductions
        float alpha = wave_sum(q * w);
        float sww = wave_sum(w * w);
        float b2 = fmaxf(fmaf(-alpha, alpha, sww), 0.0f);
        float binv = (b2 > 1e-20f) ? rsqrtf(b2) : 0.0f;
        float wn = fmaf(-alpha, q, w);
        qp = q;
        q = wn * binv;
        qbp[t] = q;                       // publish next q ASAP
        MEMFENCE();
        // shadow work (under the write->read gap)
        bool cap = (t == k);
        dval = cap ? alpha : dval;
        e2val = cap ? b2 : e2val;         // beta_{k+1}^2
        bprev = b2 * binv;                // sqrt(b2)
    }
    // peeled last step (k = 63): only alpha_63 needed
    {
        f32x2 a0 = {0.0f, 0.0f}, a1 = {0.0f, 0.0f};
        f32x2 a2 = {0.0f, 0.0f}, a3 = {0.0f, 0.0f};
        #pragma unroll
        for (int m = 0; m < 16; m += 2) {
            float4 q0 = qb[m];
            float4 q1 = qb[m + 1];
            f32x2 u01; u01.x = q0.x; u01.y = q0.y;
            f32x2 u23; u23.x = q0.z; u23.y = q0.w;
            f32x2 v01; v01.x = q1.x; v01.y = q1.y;
            f32x2 v23; v23.x = q1.z; v23.y = q1.w;
            a0 = __builtin_elementwise_fma(r2[2 * m],     u01, a0);
            a1 = __builtin_elementwise_fma(r2[2 * m + 1], u23, a1);
            a2 = __builtin_elementwise_fma(r2[2 * m + 2], v01, a2);
            a3 = __builtin_elementwise_fma(r2[2 * m + 3], v23, a3);
        }
        float w = ((a0.x + a0.y) + (a1.x + a1.y)) + ((a2.x + a2.y) + (a3.x + a3.y));
        w = fmaf(-bprev, qp, w);
        float alpha = wave_sum(q * w);
        dval = (t == NDIM - 1) ? alpha : dval;
        // lane-63 e2val stays 0 (beta_64 nonexistent; Sturm uses lanes 0..62)
    }

    sturm_out(dval, e2val, idx, t, b, out);
}

// ===== Householder path: interior indices (exact-count Sturm needs a
// ghost-free tridiagonal). Verified R12 structure. =====
template<int K0, int K1>
__device__ __forceinline__ void tri_chunk(f32x2 (&r2)[32], float& colreg,
                                          float& dval, float& e2val, const int t) {
    #pragma unroll 1
    for (int k = K0; k < K1; ++k) {
        float akt = (t > k) ? colreg : 0.0f;
        float s2 = wave_sum(akt * akt);
        float a1 = rl(akt, k + 1);
        float sigma = sqrtf(s2);
        float alpha = (a1 >= 0.0f) ? -sigma : sigma;
        e2val = (t == k) ? s2 : e2val;
        float vt = akt - ((t == k + 1) ? alpha : 0.0f);
        float vtv = 2.0f * (s2 - alpha * a1);
        float beta = (vtv > 1e-30f) ? 2.0f * __builtin_amdgcn_rcpf(vtv) : 0.0f;

        float pre_col = colreg;
        #pragma unroll
        for (int j = K0 + 1; j <= K1; ++j)
            if (j == k + 1) pre_col = (j & 1) ? r2[j >> 1].y : r2[j >> 1].x;

        f32x2 acc0 = {0.0f, 0.0f}, acc1 = {0.0f, 0.0f};
        #pragma unroll
        for (int p = K0 / 2; p < 32; ++p) {
            f32x2 a;
            a.x = rl(akt, 2 * p);
            a.y = rl(akt, 2 * p + 1);
            if (p & 1) acc1 = __builtin_elementwise_fma(r2[p], a, acc1);
            else       acc0 = __builtin_elementwise_fma(r2[p], a, acc0);
        }
        float ut = (acc0.x + acc0.y) + (acc1.x + acc1.y) - alpha * pre_col;
        float vtu = wave_sum(vt * ut);
        float c  = 0.5f * beta * beta * vtu;
        float p1 = vt * beta;
        float p2 = (t > k) ? (beta * ut - 2.0f * c * vt) : 0.0f;
        float uk1 = rl(ut, k + 1);
        float ncol = pre_col - p1 * uk1 - p2 * a1 + alpha * p2;

        f32x2 np1; np1.x = -p1; np1.y = -p1;
        f32x2 np2; np2.x = -p2; np2.y = -p2;
        #pragma unroll
        for (int p = K0 / 2; p < 32; ++p) {
            f32x2 u, a;
            u.x = rl(ut, 2 * p);
            u.y = rl(ut, 2 * p + 1);
            a.x = rl(akt, 2 * p);
            a.y = rl(akt, 2 * p + 1);
            r2[p] = __builtin_elementwise_fma(np1, u,
                    __builtin_elementwise_fma(np2, a, r2[p]));
        }
        #pragma unroll
        for (int j = K0 + 1; j <= K1; ++j) {
            if (j == k + 1) {
                if (j & 1) r2[j >> 1].y = ncol; else r2[j >> 1].x = ncol;
            }
        }
        colreg = ncol;
        dval = (t == k + 1) ? ncol : dval;
    }
}

__global__ __launch_bounds__(256, 1)
void householder_kernel(const float* __restrict__ x, const float* __restrict__ y,
                        const float* __restrict__ ws, const int* __restrict__ idxp,
                        float* __restrict__ out, int batch) {
    int idx = idxp[0];
    idx = idx < 0 ? 0 : (idx > NDIM - 1 ? NDIM - 1 : idx);
    if (idx == 0 || idx == NDIM - 1) return;   // handled by lanczos kernel

    const int t = threadIdx.x & 63;
    const int b = blockIdx.x * 4 + (threadIdx.x >> 6);
    if (b >= batch) return;

    const float xi = x[b * NDIM + t];
    const float yi = y[b * NDIM + t];
    f32x2 r2[32];
    build_rows(r2, ws, xi, yi, t);

    float colreg = r2[0].x;
    float dval = (t == 0) ? r2[0].x : 0.0f;
    float e2val = 0.0f;
    tri_chunk< 0,  8>(r2, colreg, dval, e2val, t);
    tri_chunk< 8, 16>(r2, colreg, dval, e2val, t);
    tri_chunk<16, 24>(r2, colreg, dval, e2val, t);
    tri_chunk<24, 32>(r2, colreg, dval, e2val, t);
    tri_chunk<32, 40>(r2, colreg, dval, e2val, t);
    tri_chunk<40, 48>(r2, colreg, dval, e2val, t);
    tri_chunk<48, 56>(r2, colreg, dval, e2val, t);
    tri_chunk<56, 62>(r2, colreg, dval, e2val, t);

    float e62 = rl(colreg, 63);
    e2val = (t == 62) ? e62 * e62 : e2val;
    dval = (t == 63) ? r2[31].y : dval;

    sturm_out(dval, e2val, idx, t, b, out);
}

extern "C" void kernel_launch(void* const* d_in, const int* in_sizes, int n_in,
                              void* d_out, int out_size, void* d_ws, size_t ws_size,
                              hipStream_t stream) {
    const float* x = (const float*)d_in[0];
    const float* y = (const float*)d_in[1];
    const float* A = (const float*)d_in[2];
    const float* B = (const float*)d_in[3];
    const float* C = (const float*)d_in[4];
    const int* idxp = (const int*)d_in[5];
    float* out = (float*)d_out;
    float* ws = (float*)d_ws;
    int batch = in_sizes[0] / NDIM;

    hipLaunchKernelGGL(prep_kernel, dim3(1), dim3(64), 0, stream, A, B, C, ws);
    hipLaunchKernelGGL(lanczos_kernel, dim3((batch + 3) / 4), dim3(256), 0, stream,
                       x, y, ws, idxp, out, batch);
    hipLaunchKernelGGL(householder_kernel, dim3((batch + 3) / 4), dim3(256), 0, stream,
                       x, y, ws, idxp, out, batch);
}

// Round 16
// 399.216 us; speedup vs baseline: 1.4457x; 1.1827x over previous
//
#include <hip/hip_runtime.h>
#include <math.h>

#define NDIM 64
#define KSTEPS 48
typedef float f32x2 __attribute__((ext_vector_type(2)));

#define MEMFENCE() asm volatile("" ::: "memory")

// Broadcast lane `lane`'s value to all lanes (uniform / SGPR).
__device__ __forceinline__ float rl(float v, int lane) {
    return __uint_as_float((unsigned)__builtin_amdgcn_readlane(__float_as_uint(v), lane));
}

// DPP add step with compile-time control/row mask.
template<int CTRL, int ROW_MASK>
__device__ __forceinline__ float dpp_add(float x) {
    int m = __builtin_amdgcn_update_dpp(0, __float_as_int(x), CTRL, ROW_MASK, 0xf, true);
    return x + __int_as_float(m);
}
// Full-wave64 sum via DPP; total lands in lane 63, broadcast via readlane.
__device__ __forceinline__ float wave_sum(float x) {
    x = dpp_add<0x111, 0xf>(x);   // row_shr:1
    x = dpp_add<0x112, 0xf>(x);   // row_shr:2
    x = dpp_add<0x114, 0xf>(x);   // row_shr:4
    x = dpp_add<0x118, 0xf>(x);   // row_shr:8
    x = dpp_add<0x142, 0xa>(x);   // row_bcast:15 -> rows 1,3
    x = dpp_add<0x143, 0xc>(x);   // row_bcast:31 -> row 3
    return rl(x, 63);
}
__device__ __forceinline__ float wave_min(float v) {
    #pragma unroll
    for (int off = 1; off < 64; off <<= 1) v = fminf(v, __shfl_xor(v, off, 64));
    return v;
}
__device__ __forceinline__ float wave_max(float v) {
    #pragma unroll
    for (int off = 1; off < 64; off <<= 1) v = fmaxf(v, __shfl_xor(v, off, 64));
    return v;
}

// Build symmetrized row t into r2 (32 x f32x2) using readlane broadcasts.
__device__ __forceinline__ void build_rows(f32x2 (&r2)[32], const float* ws,
                                           float xi, float yi, int t) {
    const float4* Sa4 = (const float4*)(ws + t * NDIM);
    const float4* Bh4 = (const float4*)(ws + 4096 + t * NDIM);
    const float4* Bt4 = (const float4*)(ws + 8192 + t * NDIM);
    const float4* Ch4 = (const float4*)(ws + 12288 + t * NDIM);
    const float4* Ct4 = (const float4*)(ws + 16384 + t * NDIM);
    #pragma unroll
    for (int q = 0; q < 16; ++q) {
        float4 sa = Sa4[q], bh = Bh4[q], bt = Bt4[q], ch = Ch4[q], ct = Ct4[q];
        float x0 = rl(xi, 4 * q),     y0 = rl(yi, 4 * q);
        float x1 = rl(xi, 4 * q + 1), y1 = rl(yi, 4 * q + 1);
        float x2 = rl(xi, 4 * q + 2), y2 = rl(yi, 4 * q + 2);
        float x3 = rl(xi, 4 * q + 3), y3 = rl(yi, 4 * q + 3);
        float e0 = fmaf(bh.x, x0, fmaf(bt.x, xi, fmaf(ch.x, y0, fmaf(ct.x, yi, sa.x))));
        float e1 = fmaf(bh.y, x1, fmaf(bt.y, xi, fmaf(ch.y, y1, fmaf(ct.y, yi, sa.y))));
        float e2 = fmaf(bh.z, x2, fmaf(bt.z, xi, fmaf(ch.z, y2, fmaf(ct.z, yi, sa.z))));
        float e3 = fmaf(bh.w, x3, fmaf(bt.w, xi, fmaf(ch.w, y3, fmaf(ct.w, yi, sa.w))));
        r2[2 * q].x = e0;     r2[2 * q].y = e1;
        r2[2 * q + 1].x = e2; r2[2 * q + 1].y = e3;
    }
}

// Shared tail: Gershgorin bounds over lanes < nact + 64-way Sturm multisection.
// Pad lanes (>= nact) must hold dval = +/-1e30, e2val = 0.
__device__ __forceinline__ void sturm_out(float dval, float e2val, int idx,
                                          int t, int b, float* out, int nact) {
    bool act = (t < nact);
    float eabs = sqrtf(e2val);
    float eprev = __shfl_up(eabs, 1, 64);
    eprev = (t == 0) ? 0.0f : eprev;
    float rad = eabs + eprev;
    float lo = wave_min(act ? dval - rad : 1e30f);
    float hi = wave_max(act ? dval + rad : -1e30f);
    float pad = 1e-3f + 1e-5f * fmaxf(fabsf(lo), fabsf(hi));
    lo -= pad;
    hi += pad;

    #pragma unroll 1
    for (int it = 0; it < 2; ++it) {
        float wdt = (hi - lo) * (1.0f / 65.0f);
        float s = lo + wdt * (float)(t + 1);
        float q = rl(dval, 0) - s;
        q = (fabsf(q) < 1e-12f) ? -1e-12f : q;
        int cnt = (q < 0.0f) ? 1 : 0;
        #pragma unroll
        for (int i = 1; i < NDIM; ++i) {
            q = rl(dval, i) - s - rl(e2val, i - 1) * __builtin_amdgcn_rcpf(q);
            q = (fabsf(q) < 1e-12f) ? -1e-12f : q;
            cnt += (q < 0.0f) ? 1 : 0;
        }
        unsigned long long m = __ballot(cnt <= idx);
        int p = (int)__popcll(m);
        float nlo = lo + wdt * (float)p;
        float nhi = lo + wdt * (float)(p + 1);
        lo = nlo;
        hi = (p >= 64) ? hi : nhi;
    }
    if (t == 0) out[b] = 0.5f * (lo + hi);
}

// One-time prep: Sa = 0.5(A+A^T), Bh = 0.5B, Bt = 0.5B^T, Ch = 0.5C, Ct = 0.5C^T.
__global__ __launch_bounds__(64)
void prep_kernel(const float* __restrict__ A, const float* __restrict__ B,
                 const float* __restrict__ C, float* __restrict__ ws) {
    const int t = threadIdx.x;
    float* Sa = ws;
    float* Bh = ws + 4096;
    float* Bt = ws + 8192;
    float* Ch = ws + 12288;
    float* Ct = ws + 16384;
    for (int j = 0; j < NDIM; ++j) {
        Sa[t * NDIM + j] = 0.5f * (A[t * NDIM + j] + A[j * NDIM + t]);
        Bh[t * NDIM + j] = 0.5f * B[t * NDIM + j];
        Bt[t * NDIM + j] = 0.5f * B[j * NDIM + t];
        Ch[t * NDIM + j] = 0.5f * C[t * NDIM + j];
        Ct[t * NDIM + j] = 0.5f * C[j * NDIM + t];
    }
}

// ===== Truncated Lanczos (K=48), extreme indices (idx==0 or idx==63).
// Kaniel-Paige: extremal Ritz values converge in << 48 steps for these
// spectra. Sturm runs on the 64-lane array with pad lanes at +/-1e30:
// idx==0 -> +1e30 (never counted); idx==63 -> -1e30 (always counted,
// shifting the target index by exactly 64-K so cnt<=63 selects T's largest).
// Lane K-1 e2 stays 0 (peel captures alpha only) -> padding decoupled. =====
__global__ __launch_bounds__(256, 4)
void lanczos_kernel(const float* __restrict__ x, const float* __restrict__ y,
                    const float* __restrict__ ws, const int* __restrict__ idxp,
                    float* __restrict__ out, int batch) {
    int idx = idxp[0];
    idx = idx < 0 ? 0 : (idx > NDIM - 1 ? NDIM - 1 : idx);
    if (idx != 0 && idx != NDIM - 1) return;   // interior: householder kernel

    const int t = threadIdx.x & 63;
    const int wv = threadIdx.x >> 6;
    const int b = blockIdx.x * 4 + wv;
    if (b >= batch) return;

    __shared__ float4 qbs[4][16];
    float4* qb = qbs[wv];
    float* qbp = (float*)qb;

    const float xi = x[b * NDIM + t];
    const float yi = y[b * NDIM + t];
    f32x2 r2[32];
    build_rows(r2, ws, xi, yi, t);

    // Lanczos: q0 = e_0. T diag alpha_k -> lane k, offdiag beta_{k+1}^2 -> lane k.
    const float padval = (idx == 0) ? 1e30f : -1e30f;
    float q = (t == 0) ? 1.0f : 0.0f;
    qbp[t] = q;
    MEMFENCE();
    float qp = 0.0f, bprev = 0.0f;
    float dval = padval, e2val = 0.0f;
    #pragma unroll 1
    for (int k = 0; k < KSTEPS - 1; ++k) {
        // matvec: 4 independent 8-deep pk-FMA chains
        f32x2 a0 = {0.0f, 0.0f}, a1 = {0.0f, 0.0f};
        f32x2 a2 = {0.0f, 0.0f}, a3 = {0.0f, 0.0f};
        #pragma unroll
        for (int m = 0; m < 16; m += 2) {
            float4 q0 = qb[m];
            float4 q1 = qb[m + 1];
            f32x2 u01; u01.x = q0.x; u01.y = q0.y;
            f32x2 u23; u23.x = q0.z; u23.y = q0.w;
            f32x2 v01; v01.x = q1.x; v01.y = q1.y;
            f32x2 v23; v23.x = q1.z; v23.y = q1.w;
            a0 = __builtin_elementwise_fma(r2[2 * m],     u01, a0);
            a1 = __builtin_elementwise_fma(r2[2 * m + 1], u23, a1);
            a2 = __builtin_elementwise_fma(r2[2 * m + 2], v01, a2);
            a3 = __builtin_elementwise_fma(r2[2 * m + 3], v23, a3);
        }
        float w = ((a0.x + a0.y) + (a1.x + a1.y)) + ((a2.x + a2.y) + (a3.x + a3.y));
        w = fmaf(-bprev, qp, w);
        // merged independent reductions
        float alpha = wave_sum(q * w);
        float sww = wave_sum(w * w);
        float b2 = fmaxf(fmaf(-alpha, alpha, sww), 0.0f);
        float binv = (b2 > 1e-20f) ? rsqrtf(b2) : 0.0f;
        float wn = fmaf(-alpha, q, w);
        qp = q;
        q = wn * binv;
        qbp[t] = q;                       // publish next q ASAP
        MEMFENCE();
        // shadow work (under the write->read gap)
        bool cap = (t == k);
        dval = cap ? alpha : dval;
        e2val = cap ? b2 : e2val;         // beta_{k+1}^2
        bprev = b2 * binv;                // sqrt(b2)
    }
    // peeled last step (k = KSTEPS-1): only alpha needed
    {
        f32x2 a0 = {0.0f, 0.0f}, a1 = {0.0f, 0.0f};
        f32x2 a2 = {0.0f, 0.0f}, a3 = {0.0f, 0.0f};
        #pragma unroll
        for (int m = 0; m < 16; m += 2) {
            float4 q0 = qb[m];
            float4 q1 = qb[m + 1];
            f32x2 u01; u01.x = q0.x; u01.y = q0.y;
            f32x2 u23; u23.x = q0.z; u23.y = q0.w;
            f32x2 v01; v01.x = q1.x; v01.y = q1.y;
            f32x2 v23; v23.x = q1.z; v23.y = q1.w;
            a0 = __builtin_elementwise_fma(r2[2 * m],     u01, a0);
            a1 = __builtin_elementwise_fma(r2[2 * m + 1], u23, a1);
            a2 = __builtin_elementwise_fma(r2[2 * m + 2], v01, a2);
            a3 = __builtin_elementwise_fma(r2[2 * m + 3], v23, a3);
        }
        float w = ((a0.x + a0.y) + (a1.x + a1.y)) + ((a2.x + a2.y) + (a3.x + a3.y));
        w = fmaf(-bprev, qp, w);
        float alpha = wave_sum(q * w);
        dval = (t == KSTEPS - 1) ? alpha : dval;
        // lane KSTEPS-1 e2val stays 0 -> truncated T decoupled from pads
    }

    sturm_out(dval, e2val, idx, t, b, out, KSTEPS);
}

// ===== Householder path: interior indices (exact-count Sturm needs a
// ghost-free tridiagonal). Verified R12 structure. =====
template<int K0, int K1>
__device__ __forceinline__ void tri_chunk(f32x2 (&r2)[32], float& colreg,
                                          float& dval, float& e2val, const int t) {
    #pragma unroll 1
    for (int k = K0; k < K1; ++k) {
        float akt = (t > k) ? colreg : 0.0f;
        float s2 = wave_sum(akt * akt);
        float a1 = rl(akt, k + 1);
        float sigma = sqrtf(s2);
        float alpha = (a1 >= 0.0f) ? -sigma : sigma;
        e2val = (t == k) ? s2 : e2val;
        float vt = akt - ((t == k + 1) ? alpha : 0.0f);
        float vtv = 2.0f * (s2 - alpha * a1);
        float beta = (vtv > 1e-30f) ? 2.0f * __builtin_amdgcn_rcpf(vtv) : 0.0f;

        float pre_col = colreg;
        #pragma unroll
        for (int j = K0 + 1; j <= K1; ++j)
            if (j == k + 1) pre_col = (j & 1) ? r2[j >> 1].y : r2[j >> 1].x;

        f32x2 acc0 = {0.0f, 0.0f}, acc1 = {0.0f, 0.0f};
        #pragma unroll
        for (int p = K0 / 2; p < 32; ++p) {
            f32x2 a;
            a.x = rl(akt, 2 * p);
            a.y = rl(akt, 2 * p + 1);
            if (p & 1) acc1 = __builtin_elementwise_fma(r2[p], a, acc1);
            else       acc0 = __builtin_elementwise_fma(r2[p], a, acc0);
        }
        float ut = (acc0.x + acc0.y) + (acc1.x + acc1.y) - alpha * pre_col;
        float vtu = wave_sum(vt * ut);
        float c  = 0.5f * beta * beta * vtu;
        float p1 = vt * beta;
        float p2 = (t > k) ? (beta * ut - 2.0f * c * vt) : 0.0f;
        float uk1 = rl(ut, k + 1);
        float ncol = pre_col - p1 * uk1 - p2 * a1 + alpha * p2;

        f32x2 np1; np1.x = -p1; np1.y = -p1;
        f32x2 np2; np2.x = -p2; np2.y = -p2;
        #pragma unroll
        for (int p = K0 / 2; p < 32; ++p) {
            f32x2 u, a;
            u.x = rl(ut, 2 * p);
            u.y = rl(ut, 2 * p + 1);
            a.x = rl(akt, 2 * p);
            a.y = rl(akt, 2 * p + 1);
            r2[p] = __builtin_elementwise_fma(np1, u,
                    __builtin_elementwise_fma(np2, a, r2[p]));
        }
        #pragma unroll
        for (int j = K0 + 1; j <= K1; ++j) {
            if (j == k + 1) {
                if (j & 1) r2[j >> 1].y = ncol; else r2[j >> 1].x = ncol;
            }
        }
        colreg = ncol;
        dval = (t == k + 1) ? ncol : dval;
    }
}

__global__ __launch_bounds__(256, 1)
void householder_kernel(const float* __restrict__ x, const float* __restrict__ y,
                        const float* __restrict__ ws, const int* __restrict__ idxp,
                        float* __restrict__ out, int batch) {
    int idx = idxp[0];
    idx = idx < 0 ? 0 : (idx > NDIM - 1 ? NDIM - 1 : idx);
    if (idx == 0 || idx == NDIM - 1) return;   // handled by lanczos kernel

    const int t = threadIdx.x & 63;
    const int b = blockIdx.x * 4 + (threadIdx.x >> 6);
    if (b >= batch) return;

    const float xi = x[b * NDIM + t];
    const float yi = y[b * NDIM + t];
    f32x2 r2[32];
    build_rows(r2, ws, xi, yi, t);

    float colreg = r2[0].x;
    float dval = (t == 0) ? r2[0].x : 0.0f;
    float e2val = 0.0f;
    tri_chunk< 0,  8>(r2, colreg, dval, e2val, t);
    tri_chunk< 8, 16>(r2, colreg, dval, e2val, t);
    tri_chunk<16, 24>(r2, colreg, dval, e2val, t);
    tri_chunk<24, 32>(r2, colreg, dval, e2val, t);
    tri_chunk<32, 40>(r2, colreg, dval, e2val, t);
    tri_chunk<40, 48>(r2, colreg, dval, e2val, t);
    tri_chunk<48, 56>(r2, colreg, dval, e2val, t);
    tri_chunk<56, 62>(r2, colreg, dval, e2val, t);

    float e62 = rl(colreg, 63);
    e2val = (t == 62) ? e62 * e62 : e2val;
    dval = (t == 63) ? r2[31].y : dval;

    sturm_out(dval, e2val, idx, t, b, out, NDIM);
}

extern "C" void kernel_launch(void* const* d_in, const int* in_sizes, int n_in,
                              void* d_out, int out_size, void* d_ws, size_t ws_size,
                              hipStream_t stream) {
    const float* x = (const float*)d_in[0];
    const float* y = (const float*)d_in[1];
    const float* A = (const float*)d_in[2];
    const float* B = (const float*)d_in[3];
    const float* C = (const float*)d_in[4];
    const int* idxp = (const int*)d_in[5];
    float* out = (float*)d_out;
    float* ws = (float*)d_ws;
    int batch = in_sizes[0] / NDIM;

    hipLaunchKernelGGL(prep_kernel, dim3(1), dim3(64), 0, stream, A, B, C, ws);
    hipLaunchKernelGGL(lanczos_kernel, dim3((batch + 3) / 4), dim3(256), 0, stream,
                       x, y, ws, idxp, out, batch);
    hipLaunchKernelGGL(householder_kernel, dim3((batch + 3) / 4), dim3(256), 0, stream,
                       x, y, ws, idxp, out, batch);
}

// Round 17
// 398.618 us; speedup vs baseline: 1.4479x; 1.0015x over previous
//
#include <hip/hip_runtime.h>
#include <math.h>

#define NDIM 64
#define KSTEPS 48
typedef float f32x2 __attribute__((ext_vector_type(2)));

#define MEMFENCE() asm volatile("" ::: "memory")

// Broadcast lane `lane`'s value to all lanes (uniform / SGPR).
__device__ __forceinline__ float rl(float v, int lane) {
    return __uint_as_float((unsigned)__builtin_amdgcn_readlane(__float_as_uint(v), lane));
}

// DPP add step with compile-time control/row mask.
template<int CTRL, int ROW_MASK>
__device__ __forceinline__ float dpp_add(float x) {
    int m = __builtin_amdgcn_update_dpp(0, __float_as_int(x), CTRL, ROW_MASK, 0xf, true);
    return x + __int_as_float(m);
}
// Full-wave64 sum via DPP; total lands in lane 63, broadcast via readlane.
__device__ __forceinline__ float wave_sum(float x) {
    x = dpp_add<0x111, 0xf>(x);   // row_shr:1
    x = dpp_add<0x112, 0xf>(x);   // row_shr:2
    x = dpp_add<0x114, 0xf>(x);   // row_shr:4
    x = dpp_add<0x118, 0xf>(x);   // row_shr:8
    x = dpp_add<0x142, 0xa>(x);   // row_bcast:15 -> rows 1,3
    x = dpp_add<0x143, 0xc>(x);   // row_bcast:31 -> row 3
    return rl(x, 63);
}
__device__ __forceinline__ float wave_min(float v) {
    #pragma unroll
    for (int off = 1; off < 64; off <<= 1) v = fminf(v, __shfl_xor(v, off, 64));
    return v;
}
__device__ __forceinline__ float wave_max(float v) {
    #pragma unroll
    for (int off = 1; off < 64; off <<= 1) v = fmaxf(v, __shfl_xor(v, off, 64));
    return v;
}

// Build symmetrized row t into r2 (32 x f32x2) using readlane broadcasts.
__device__ __forceinline__ void build_rows(f32x2 (&r2)[32], const float* ws,
                                           float xi, float yi, int t) {
    const float4* Sa4 = (const float4*)(ws + t * NDIM);
    const float4* Bh4 = (const float4*)(ws + 4096 + t * NDIM);
    const float4* Bt4 = (const float4*)(ws + 8192 + t * NDIM);
    const float4* Ch4 = (const float4*)(ws + 12288 + t * NDIM);
    const float4* Ct4 = (const float4*)(ws + 16384 + t * NDIM);
    #pragma unroll
    for (int q = 0; q < 16; ++q) {
        float4 sa = Sa4[q], bh = Bh4[q], bt = Bt4[q], ch = Ch4[q], ct = Ct4[q];
        float x0 = rl(xi, 4 * q),     y0 = rl(yi, 4 * q);
        float x1 = rl(xi, 4 * q + 1), y1 = rl(yi, 4 * q + 1);
        float x2 = rl(xi, 4 * q + 2), y2 = rl(yi, 4 * q + 2);
        float x3 = rl(xi, 4 * q + 3), y3 = rl(yi, 4 * q + 3);
        float e0 = fmaf(bh.x, x0, fmaf(bt.x, xi, fmaf(ch.x, y0, fmaf(ct.x, yi, sa.x))));
        float e1 = fmaf(bh.y, x1, fmaf(bt.y, xi, fmaf(ch.y, y1, fmaf(ct.y, yi, sa.y))));
        float e2 = fmaf(bh.z, x2, fmaf(bt.z, xi, fmaf(ch.z, y2, fmaf(ct.z, yi, sa.z))));
        float e3 = fmaf(bh.w, x3, fmaf(bt.w, xi, fmaf(ch.w, y3, fmaf(ct.w, yi, sa.w))));
        r2[2 * q].x = e0;     r2[2 * q].y = e1;
        r2[2 * q + 1].x = e2; r2[2 * q + 1].y = e3;
    }
}

// Shared tail: stash (d_t, e^2_{t-1}) in per-wave LDS, Gershgorin bounds over
// lanes < NACT, then 64-way Sturm multisection with the serial recurrence
// reading (d_i, e2_{i-1}) as ds_read_b64 broadcasts (loop length NACT only).
template<int NACT>
__device__ __forceinline__ void sturm_out(float dval, float e2val, int idx,
                                          int t, int b, float* out, float2* dep) {
    float e2prev = __shfl_up(e2val, 1, 64);
    e2prev = (t == 0) ? 0.0f : e2prev;
    float2 dp; dp.x = dval; dp.y = e2prev;
    dep[t] = dp;
    MEMFENCE();

    bool act = (t < NACT);
    float eabs = sqrtf(e2val);
    float eprev = __shfl_up(eabs, 1, 64);
    eprev = (t == 0) ? 0.0f : eprev;
    float rad = eabs + eprev;
    float lo = wave_min(act ? dval - rad : 1e30f);
    float hi = wave_max(act ? dval + rad : -1e30f);
    float pad = 1e-3f + 1e-5f * fmaxf(fabsf(lo), fabsf(hi));
    lo -= pad;
    hi += pad;

    #pragma unroll 1
    for (int it = 0; it < 2; ++it) {
        float wdt = (hi - lo) * (1.0f / 65.0f);
        float s = lo + wdt * (float)(t + 1);
        float2 p0 = dep[0];
        float q = p0.x - s;
        q = (fabsf(q) < 1e-12f) ? -1e-12f : q;
        int cnt = (q < 0.0f) ? 1 : 0;
        #pragma unroll
        for (int i = 1; i < NACT; ++i) {
            float2 pi = dep[i];
            q = pi.x - s - pi.y * __builtin_amdgcn_rcpf(q);
            q = (fabsf(q) < 1e-12f) ? -1e-12f : q;
            cnt += (q < 0.0f) ? 1 : 0;
        }
        unsigned long long m = __ballot(cnt <= idx);
        int p = (int)__popcll(m);
        float nlo = lo + wdt * (float)p;
        float nhi = lo + wdt * (float)(p + 1);
        lo = nlo;
        hi = (p >= 64) ? hi : nhi;
    }
    if (t == 0) out[b] = 0.5f * (lo + hi);
}

// One-time prep: Sa = 0.5(A+A^T), Bh = 0.5B, Bt = 0.5B^T, Ch = 0.5C, Ct = 0.5C^T.
__global__ __launch_bounds__(64)
void prep_kernel(const float* __restrict__ A, const float* __restrict__ B,
                 const float* __restrict__ C, float* __restrict__ ws) {
    const int t = threadIdx.x;
    float* Sa = ws;
    float* Bh = ws + 4096;
    float* Bt = ws + 8192;
    float* Ch = ws + 12288;
    float* Ct = ws + 16384;
    for (int j = 0; j < NDIM; ++j) {
        Sa[t * NDIM + j] = 0.5f * (A[t * NDIM + j] + A[j * NDIM + t]);
        Bh[t * NDIM + j] = 0.5f * B[t * NDIM + j];
        Bt[t * NDIM + j] = 0.5f * B[j * NDIM + t];
        Ch[t * NDIM + j] = 0.5f * C[t * NDIM + j];
        Ct[t * NDIM + j] = 0.5f * C[j * NDIM + t];
    }
}

// ===== Truncated Lanczos (K=48), extreme indices (idx==0 or idx==63).
// Sturm runs on the K-dim T only; for idx==63 the target maps to T's largest
// (idx_eff = KSTEPS-1). Lane KSTEPS-1's e2 stays 0 (peel captures alpha only).
__global__ __launch_bounds__(256, 4)
void lanczos_kernel(const float* __restrict__ x, const float* __restrict__ y,
                    const float* __restrict__ ws, const int* __restrict__ idxp,
                    float* __restrict__ out, int batch) {
    int idx = idxp[0];
    idx = idx < 0 ? 0 : (idx > NDIM - 1 ? NDIM - 1 : idx);
    if (idx != 0 && idx != NDIM - 1) return;   // interior: householder kernel
    const int idx_eff = (idx == 0) ? 0 : (KSTEPS - 1);

    const int t = threadIdx.x & 63;
    const int wv = threadIdx.x >> 6;
    const int b = blockIdx.x * 4 + wv;
    if (b >= batch) return;

    __shared__ float4 qbs[4][16];
    __shared__ float2 des[4][64];
    float4* qb = qbs[wv];
    float* qbp = (float*)qb;

    const float xi = x[b * NDIM + t];
    const float yi = y[b * NDIM + t];
    f32x2 r2[32];
    build_rows(r2, ws, xi, yi, t);

    // Lanczos: q0 = e_0. T diag alpha_k -> lane k, offdiag beta_{k+1}^2 -> lane k.
    float q = (t == 0) ? 1.0f : 0.0f;
    qbp[t] = q;
    MEMFENCE();
    float qp = 0.0f, bprev = 0.0f;
    float dval = 0.0f, e2val = 0.0f;
    #pragma unroll 1
    for (int k = 0; k < KSTEPS - 1; ++k) {
        // matvec: 4 independent 8-deep pk-FMA chains
        f32x2 a0 = {0.0f, 0.0f}, a1 = {0.0f, 0.0f};
        f32x2 a2 = {0.0f, 0.0f}, a3 = {0.0f, 0.0f};
        #pragma unroll
        for (int m = 0; m < 16; m += 2) {
            float4 q0 = qb[m];
            float4 q1 = qb[m + 1];
            f32x2 u01; u01.x = q0.x; u01.y = q0.y;
            f32x2 u23; u23.x = q0.z; u23.y = q0.w;
            f32x2 v01; v01.x = q1.x; v01.y = q1.y;
            f32x2 v23; v23.x = q1.z; v23.y = q1.w;
            a0 = __builtin_elementwise_fma(r2[2 * m],     u01, a0);
            a1 = __builtin_elementwise_fma(r2[2 * m + 1], u23, a1);
            a2 = __builtin_elementwise_fma(r2[2 * m + 2], v01, a2);
            a3 = __builtin_elementwise_fma(r2[2 * m + 3], v23, a3);
        }
        f32x2 s01 = a0 + a1;
        f32x2 s23 = a2 + a3;
        f32x2 st = s01 + s23;
        float w = st.x + st.y;
        w = fmaf(-bprev, qp, w);
        // merged independent reductions
        float alpha = wave_sum(q * w);
        float sww = wave_sum(w * w);
        float b2 = fmaxf(fmaf(-alpha, alpha, sww), 0.0f);
        float binv = (b2 > 1e-20f) ? rsqrtf(b2) : 0.0f;
        float wn = fmaf(-alpha, q, w);
        qp = q;
        q = wn * binv;
        qbp[t] = q;                       // publish next q ASAP
        MEMFENCE();
        // shadow work (under the write->read gap)
        bool cap = (t == k);
        dval = cap ? alpha : dval;
        e2val = cap ? b2 : e2val;         // beta_{k+1}^2
        bprev = b2 * binv;                // sqrt(b2)
    }
    // peeled last step (k = KSTEPS-1): only alpha needed
    {
        f32x2 a0 = {0.0f, 0.0f}, a1 = {0.0f, 0.0f};
        f32x2 a2 = {0.0f, 0.0f}, a3 = {0.0f, 0.0f};
        #pragma unroll
        for (int m = 0; m < 16; m += 2) {
            float4 q0 = qb[m];
            float4 q1 = qb[m + 1];
            f32x2 u01; u01.x = q0.x; u01.y = q0.y;
            f32x2 u23; u23.x = q0.z; u23.y = q0.w;
            f32x2 v01; v01.x = q1.x; v01.y = q1.y;
            f32x2 v23; v23.x = q1.z; v23.y = q1.w;
            a0 = __builtin_elementwise_fma(r2[2 * m],     u01, a0);
            a1 = __builtin_elementwise_fma(r2[2 * m + 1], u23, a1);
            a2 = __builtin_elementwise_fma(r2[2 * m + 2], v01, a2);
            a3 = __builtin_elementwise_fma(r2[2 * m + 3], v23, a3);
        }
        f32x2 s01 = a0 + a1;
        f32x2 s23 = a2 + a3;
        f32x2 st = s01 + s23;
        float w = st.x + st.y;
        w = fmaf(-bprev, qp, w);
        float alpha = wave_sum(q * w);
        dval = (t == KSTEPS - 1) ? alpha : dval;
        // lane KSTEPS-1 e2val stays 0 -> truncated T decoupled
    }

    sturm_out<KSTEPS>(dval, e2val, idx_eff, t, b, out, des[wv]);
}

// ===== Householder path: interior indices (exact-count Sturm needs a
// ghost-free tridiagonal). Verified R12 structure. =====
template<int K0, int K1>
__device__ __forceinline__ void tri_chunk(f32x2 (&r2)[32], float& colreg,
                                          float& dval, float& e2val, const int t) {
    #pragma unroll 1
    for (int k = K0; k < K1; ++k) {
        float akt = (t > k) ? colreg : 0.0f;
        float s2 = wave_sum(akt * akt);
        float a1 = rl(akt, k + 1);
        float sigma = sqrtf(s2);
        float alpha = (a1 >= 0.0f) ? -sigma : sigma;
        e2val = (t == k) ? s2 : e2val;
        float vt = akt - ((t == k + 1) ? alpha : 0.0f);
        float vtv = 2.0f * (s2 - alpha * a1);
        float beta = (vtv > 1e-30f) ? 2.0f * __builtin_amdgcn_rcpf(vtv) : 0.0f;

        float pre_col = colreg;
        #pragma unroll
        for (int j = K0 + 1; j <= K1; ++j)
            if (j == k + 1) pre_col = (j & 1) ? r2[j >> 1].y : r2[j >> 1].x;

        f32x2 acc0 = {0.0f, 0.0f}, acc1 = {0.0f, 0.0f};
        #pragma unroll
        for (int p = K0 / 2; p < 32; ++p) {
            f32x2 a;
            a.x = rl(akt, 2 * p);
            a.y = rl(akt, 2 * p + 1);
            if (p & 1) acc1 = __builtin_elementwise_fma(r2[p], a, acc1);
            else       acc0 = __builtin_elementwise_fma(r2[p], a, acc0);
        }
        float ut = (acc0.x + acc0.y) + (acc1.x + acc1.y) - alpha * pre_col;
        float vtu = wave_sum(vt * ut);
        float c  = 0.5f * beta * beta * vtu;
        float p1 = vt * beta;
        float p2 = (t > k) ? (beta * ut - 2.0f * c * vt) : 0.0f;
        float uk1 = rl(ut, k + 1);
        float ncol = pre_col - p1 * uk1 - p2 * a1 + alpha * p2;

        f32x2 np1; np1.x = -p1; np1.y = -p1;
        f32x2 np2; np2.x = -p2; np2.y = -p2;
        #pragma unroll
        for (int p = K0 / 2; p < 32; ++p) {
            f32x2 u, a;
            u.x = rl(ut, 2 * p);
            u.y = rl(ut, 2 * p + 1);
            a.x = rl(akt, 2 * p);
            a.y = rl(akt, 2 * p + 1);
            r2[p] = __builtin_elementwise_fma(np1, u,
                    __builtin_elementwise_fma(np2, a, r2[p]));
        }
        #pragma unroll
        for (int j = K0 + 1; j <= K1; ++j) {
            if (j == k + 1) {
                if (j & 1) r2[j >> 1].y = ncol; else r2[j >> 1].x = ncol;
            }
        }
        colreg = ncol;
        dval = (t == k + 1) ? ncol : dval;
    }
}

__global__ __launch_bounds__(256, 1)
void householder_kernel(const float* __restrict__ x, const float* __restrict__ y,
                        const float* __restrict__ ws, const int* __restrict__ idxp,
                        float* __restrict__ out, int batch) {
    int idx = idxp[0];
    idx = idx < 0 ? 0 : (idx > NDIM - 1 ? NDIM - 1 : idx);
    if (idx == 0 || idx == NDIM - 1) return;   // handled by lanczos kernel

    const int t = threadIdx.x & 63;
    const int wv = threadIdx.x >> 6;
    const int b = blockIdx.x * 4 + wv;
    if (b >= batch) return;

    __shared__ float2 des[4][64];

    const float xi = x[b * NDIM + t];
    const float yi = y[b * NDIM + t];
    f32x2 r2[32];
    build_rows(r2, ws, xi, yi, t);

    float colreg = r2[0].x;
    float dval = (t == 0) ? r2[0].x : 0.0f;
    float e2val = 0.0f;
    tri_chunk< 0,  8>(r2, colreg, dval, e2val, t);
    tri_chunk< 8, 16>(r2, colreg, dval, e2val, t);
    tri_chunk<16, 24>(r2, colreg, dval, e2val, t);
    tri_chunk<24, 32>(r2, colreg, dval, e2val, t);
    tri_chunk<32, 40>(r2, colreg, dval, e2val, t);
    tri_chunk<40, 48>(r2, colreg, dval, e2val, t);
    tri_chunk<48, 56>(r2, colreg, dval, e2val, t);
    tri_chunk<56, 62>(r2, colreg, dval, e2val, t);

    float e62 = rl(colreg, 63);
    e2val = (t == 62) ? e62 * e62 : e2val;
    dval = (t == 63) ? r2[31].y : dval;

    sturm_out<NDIM>(dval, e2val, idx, t, b, out, des[wv]);
}

extern "C" void kernel_launch(void* const* d_in, const int* in_sizes, int n_in,
                              void* d_out, int out_size, void* d_ws, size_t ws_size,
                              hipStream_t stream) {
    const float* x = (const float*)d_in[0];
    const float* y = (const float*)d_in[1];
    const float* A = (const float*)d_in[2];
    const float* B = (const float*)d_in[3];
    const float* C = (const float*)d_in[4];
    const int* idxp = (const int*)d_in[5];
    float* out = (float*)d_out;
    float* ws = (float*)d_ws;
    int batch = in_sizes[0] / NDIM;

    hipLaunchKernelGGL(prep_kernel, dim3(1), dim3(64), 0, stream, A, B, C, ws);
    hipLaunchKernelGGL(lanczos_kernel, dim3((batch + 3) / 4), dim3(256), 0, stream,
                       x, y, ws, idxp, out, batch);
    hipLaunchKernelGGL(householder_kernel, dim3((batch + 3) / 4), dim3(256), 0, stream,
                       x, y, ws, idxp, out, batch);
}

// Round 18
// 379.506 us; speedup vs baseline: 1.5208x; 1.0504x over previous
//
#include <hip/hip_runtime.h>
#include <math.h>

#define NDIM 64
#define KSTEPS 48
typedef float f32x2 __attribute__((ext_vector_type(2)));

#define MEMFENCE() asm volatile("" ::: "memory")

// Broadcast lane `lane`'s value to all lanes (uniform / SGPR).
__device__ __forceinline__ float rl(float v, int lane) {
    return __uint_as_float((unsigned)__builtin_amdgcn_readlane(__float_as_uint(v), lane));
}

// DPP add step with compile-time control/row mask.
template<int CTRL, int ROW_MASK>
__device__ __forceinline__ float dpp_add(float x) {
    int m = __builtin_amdgcn_update_dpp(0, __float_as_int(x), CTRL, ROW_MASK, 0xf, true);
    return x + __int_as_float(m);
}
// Full-wave64 sum via DPP; total lands in lane 63, broadcast via readlane.
__device__ __forceinline__ float wave_sum(float x) {
    x = dpp_add<0x111, 0xf>(x);   // row_shr:1
    x = dpp_add<0x112, 0xf>(x);   // row_shr:2
    x = dpp_add<0x114, 0xf>(x);   // row_shr:4
    x = dpp_add<0x118, 0xf>(x);   // row_shr:8
    x = dpp_add<0x142, 0xa>(x);   // row_bcast:15 -> rows 1,3
    x = dpp_add<0x143, 0xc>(x);   // row_bcast:31 -> row 3
    return rl(x, 63);
}
__device__ __forceinline__ float wave_min(float v) {
    #pragma unroll
    for (int off = 1; off < 64; off <<= 1) v = fminf(v, __shfl_xor(v, off, 64));
    return v;
}
__device__ __forceinline__ float wave_max(float v) {
    #pragma unroll
    for (int off = 1; off < 64; off <<= 1) v = fmaxf(v, __shfl_xor(v, off, 64));
    return v;
}

// Build symmetrized row t into r2 (32 x f32x2) using readlane broadcasts.
__device__ __forceinline__ void build_rows(f32x2 (&r2)[32], const float* ws,
                                           float xi, float yi, int t) {
    const float4* Sa4 = (const float4*)(ws + t * NDIM);
    const float4* Bh4 = (const float4*)(ws + 4096 + t * NDIM);
    const float4* Bt4 = (const float4*)(ws + 8192 + t * NDIM);
    const float4* Ch4 = (const float4*)(ws + 12288 + t * NDIM);
    const float4* Ct4 = (const float4*)(ws + 16384 + t * NDIM);
    #pragma unroll
    for (int q = 0; q < 16; ++q) {
        float4 sa = Sa4[q], bh = Bh4[q], bt = Bt4[q], ch = Ch4[q], ct = Ct4[q];
        float x0 = rl(xi, 4 * q),     y0 = rl(yi, 4 * q);
        float x1 = rl(xi, 4 * q + 1), y1 = rl(yi, 4 * q + 1);
        float x2 = rl(xi, 4 * q + 2), y2 = rl(yi, 4 * q + 2);
        float x3 = rl(xi, 4 * q + 3), y3 = rl(yi, 4 * q + 3);
        float e0 = fmaf(bh.x, x0, fmaf(bt.x, xi, fmaf(ch.x, y0, fmaf(ct.x, yi, sa.x))));
        float e1 = fmaf(bh.y, x1, fmaf(bt.y, xi, fmaf(ch.y, y1, fmaf(ct.y, yi, sa.y))));
        float e2 = fmaf(bh.z, x2, fmaf(bt.z, xi, fmaf(ch.z, y2, fmaf(ct.z, yi, sa.z))));
        float e3 = fmaf(bh.w, x3, fmaf(bt.w, xi, fmaf(ch.w, y3, fmaf(ct.w, yi, sa.w))));
        r2[2 * q].x = e0;     r2[2 * q].y = e1;
        r2[2 * q + 1].x = e2; r2[2 * q + 1].y = e3;
    }
}

// Shared tail: Gershgorin bounds over lanes < NACT + 64-way Sturm multisection
// (register/readlane form; recurrence length NACT at compile time).
template<int NACT>
__device__ __forceinline__ void sturm_out(float dval, float e2val, int idx,
                                          int t, int b, float* out) {
    bool act = (t < NACT);
    float eabs = sqrtf(e2val);
    float eprev = __shfl_up(eabs, 1, 64);
    eprev = (t == 0) ? 0.0f : eprev;
    float rad = eabs + eprev;
    float lo = wave_min(act ? dval - rad : 1e30f);
    float hi = wave_max(act ? dval + rad : -1e30f);
    float pad = 1e-3f + 1e-5f * fmaxf(fabsf(lo), fabsf(hi));
    lo -= pad;
    hi += pad;

    #pragma unroll 1
    for (int it = 0; it < 2; ++it) {
        float wdt = (hi - lo) * (1.0f / 65.0f);
        float s = lo + wdt * (float)(t + 1);
        float q = rl(dval, 0) - s;
        q = (fabsf(q) < 1e-12f) ? -1e-12f : q;
        int cnt = (q < 0.0f) ? 1 : 0;
        #pragma unroll
        for (int i = 1; i < NACT; ++i) {
            q = rl(dval, i) - s - rl(e2val, i - 1) * __builtin_amdgcn_rcpf(q);
            q = (fabsf(q) < 1e-12f) ? -1e-12f : q;
            cnt += (q < 0.0f) ? 1 : 0;
        }
        unsigned long long m = __ballot(cnt <= idx);
        int p = (int)__popcll(m);
        float nlo = lo + wdt * (float)p;
        float nhi = lo + wdt * (float)(p + 1);
        lo = nlo;
        hi = (p >= 64) ? hi : nhi;
    }
    if (t == 0) out[b] = 0.5f * (lo + hi);
}

// One-time prep: Sa = 0.5(A+A^T), Bh = 0.5B, Bt = 0.5B^T, Ch = 0.5C, Ct = 0.5C^T.
__global__ __launch_bounds__(64)
void prep_kernel(const float* __restrict__ A, const float* __restrict__ B,
                 const float* __restrict__ C, float* __restrict__ ws) {
    const int t = threadIdx.x;
    float* Sa = ws;
    float* Bh = ws + 4096;
    float* Bt = ws + 8192;
    float* Ch = ws + 12288;
    float* Ct = ws + 16384;
    for (int j = 0; j < NDIM; ++j) {
        Sa[t * NDIM + j] = 0.5f * (A[t * NDIM + j] + A[j * NDIM + t]);
        Bh[t * NDIM + j] = 0.5f * B[t * NDIM + j];
        Bt[t * NDIM + j] = 0.5f * B[j * NDIM + t];
        Ch[t * NDIM + j] = 0.5f * C[t * NDIM + j];
        Ct[t * NDIM + j] = 0.5f * C[j * NDIM + t];
    }
}

// ===== Truncated Lanczos (K=48), extreme indices (idx==0 or idx==63).
// q-buffer typed f32x2: ds_read_b64 results feed v_pk_fma directly (no
// repack movs). Sturm on the K-dim T only (idx==63 -> T's largest).
__global__ __launch_bounds__(256, 4)
void lanczos_kernel(const float* __restrict__ x, const float* __restrict__ y,
                    const float* __restrict__ ws, const int* __restrict__ idxp,
                    float* __restrict__ out, int batch) {
    int idx = idxp[0];
    idx = idx < 0 ? 0 : (idx > NDIM - 1 ? NDIM - 1 : idx);
    if (idx != 0 && idx != NDIM - 1) return;   // interior: householder kernel
    const int idx_eff = (idx == 0) ? 0 : (KSTEPS - 1);

    const int t = threadIdx.x & 63;
    const int wv = threadIdx.x >> 6;
    const int b = blockIdx.x * 4 + wv;
    if (b >= batch) return;

    __shared__ f32x2 qbs[4][64];
    f32x2* qb2 = qbs[wv];
    float* qbp = (float*)qb2;

    const float xi = x[b * NDIM + t];
    const float yi = y[b * NDIM + t];
    f32x2 r2[32];
    build_rows(r2, ws, xi, yi, t);

    // Lanczos: q0 = e_0. T diag alpha_k -> lane k, offdiag beta_{k+1}^2 -> lane k.
    float q = (t == 0) ? 1.0f : 0.0f;
    qbp[t] = q;
    MEMFENCE();
    float qp = 0.0f, bprev = 0.0f;
    float dval = 0.0f, e2val = 0.0f;
    #pragma unroll 1
    for (int k = 0; k < KSTEPS - 1; ++k) {
        // matvec: 4 independent 8-deep pk-FMA chains; operands direct from LDS
        f32x2 a0 = {0.0f, 0.0f}, a1 = {0.0f, 0.0f};
        f32x2 a2 = {0.0f, 0.0f}, a3 = {0.0f, 0.0f};
        #pragma unroll
        for (int m = 0; m < 32; m += 4) {
            a0 = __builtin_elementwise_fma(r2[m],     qb2[m],     a0);
            a1 = __builtin_elementwise_fma(r2[m + 1], qb2[m + 1], a1);
            a2 = __builtin_elementwise_fma(r2[m + 2], qb2[m + 2], a2);
            a3 = __builtin_elementwise_fma(r2[m + 3], qb2[m + 3], a3);
        }
        f32x2 st = (a0 + a1) + (a2 + a3);
        float w = st.x + st.y;
        w = fmaf(-bprev, qp, w);
        // merged independent reductions
        float alpha = wave_sum(q * w);
        float sww = wave_sum(w * w);
        float b2 = fmaxf(fmaf(-alpha, alpha, sww), 0.0f);
        float binv = (b2 > 1e-20f) ? rsqrtf(b2) : 0.0f;
        float wn = fmaf(-alpha, q, w);
        qp = q;
        q = wn * binv;
        qbp[t] = q;                       // publish next q ASAP
        MEMFENCE();
        // shadow work (under the write->read gap)
        bool cap = (t == k);
        dval = cap ? alpha : dval;
        e2val = cap ? b2 : e2val;         // beta_{k+1}^2
        bprev = b2 * binv;                // sqrt(b2)
    }
    // peeled last step (k = KSTEPS-1): only alpha needed
    {
        f32x2 a0 = {0.0f, 0.0f}, a1 = {0.0f, 0.0f};
        f32x2 a2 = {0.0f, 0.0f}, a3 = {0.0f, 0.0f};
        #pragma unroll
        for (int m = 0; m < 32; m += 4) {
            a0 = __builtin_elementwise_fma(r2[m],     qb2[m],     a0);
            a1 = __builtin_elementwise_fma(r2[m + 1], qb2[m + 1], a1);
            a2 = __builtin_elementwise_fma(r2[m + 2], qb2[m + 2], a2);
            a3 = __builtin_elementwise_fma(r2[m + 3], qb2[m + 3], a3);
        }
        f32x2 st = (a0 + a1) + (a2 + a3);
        float w = st.x + st.y;
        w = fmaf(-bprev, qp, w);
        float alpha = wave_sum(q * w);
        dval = (t == KSTEPS - 1) ? alpha : dval;
        // lane KSTEPS-1 e2val stays 0 -> truncated T decoupled
    }

    sturm_out<KSTEPS>(dval, e2val, idx_eff, t, b, out);
}

// ===== Householder path: interior indices (exact-count Sturm needs a
// ghost-free tridiagonal). Verified R12 structure. =====
template<int K0, int K1>
__device__ __forceinline__ void tri_chunk(f32x2 (&r2)[32], float& colreg,
                                          float& dval, float& e2val, const int t) {
    #pragma unroll 1
    for (int k = K0; k < K1; ++k) {
        float akt = (t > k) ? colreg : 0.0f;
        float s2 = wave_sum(akt * akt);
        float a1 = rl(akt, k + 1);
        float sigma = sqrtf(s2);
        float alpha = (a1 >= 0.0f) ? -sigma : sigma;
        e2val = (t == k) ? s2 : e2val;
        float vt = akt - ((t == k + 1) ? alpha : 0.0f);
        float vtv = 2.0f * (s2 - alpha * a1);
        float beta = (vtv > 1e-30f) ? 2.0f * __builtin_amdgcn_rcpf(vtv) : 0.0f;

        float pre_col = colreg;
        #pragma unroll
        for (int j = K0 + 1; j <= K1; ++j)
            if (j == k + 1) pre_col = (j & 1) ? r2[j >> 1].y : r2[j >> 1].x;

        f32x2 acc0 = {0.0f, 0.0f}, acc1 = {0.0f, 0.0f};
        #pragma unroll
        for (int p = K0 / 2; p < 32; ++p) {
            f32x2 a;
            a.x = rl(akt, 2 * p);
            a.y = rl(akt, 2 * p + 1);
            if (p & 1) acc1 = __builtin_elementwise_fma(r2[p], a, acc1);
            else       acc0 = __builtin_elementwise_fma(r2[p], a, acc0);
        }
        float ut = (acc0.x + acc0.y) + (acc1.x + acc1.y) - alpha * pre_col;
        float vtu = wave_sum(vt * ut);
        float c  = 0.5f * beta * beta * vtu;
        float p1 = vt * beta;
        float p2 = (t > k) ? (beta * ut - 2.0f * c * vt) : 0.0f;
        float uk1 = rl(ut, k + 1);
        float ncol = pre_col - p1 * uk1 - p2 * a1 + alpha * p2;

        f32x2 np1; np1.x = -p1; np1.y = -p1;
        f32x2 np2; np2.x = -p2; np2.y = -p2;
        #pragma unroll
        for (int p = K0 / 2; p < 32; ++p) {
            f32x2 u, a;
            u.x = rl(ut, 2 * p);
            u.y = rl(ut, 2 * p + 1);
            a.x = rl(akt, 2 * p);
            a.y = rl(akt, 2 * p + 1);
            r2[p] = __builtin_elementwise_fma(np1, u,
                    __builtin_elementwise_fma(np2, a, r2[p]));
        }
        #pragma unroll
        for (int j = K0 + 1; j <= K1; ++j) {
            if (j == k + 1) {
                if (j & 1) r2[j >> 1].y = ncol; else r2[j >> 1].x = ncol;
            }
        }
        colreg = ncol;
        dval = (t == k + 1) ? ncol : dval;
    }
}

__global__ __launch_bounds__(256, 1)
void householder_kernel(const float* __restrict__ x, const float* __restrict__ y,
                        const float* __restrict__ ws, const int* __restrict__ idxp,
                        float* __restrict__ out, int batch) {
    int idx = idxp[0];
    idx = idx < 0 ? 0 : (idx > NDIM - 1 ? NDIM - 1 : idx);
    if (idx == 0 || idx == NDIM - 1) return;   // handled by lanczos kernel

    const int t = threadIdx.x & 63;
    const int b = blockIdx.x * 4 + (threadIdx.x >> 6);
    if (b >= batch) return;

    const float xi = x[b * NDIM + t];
    const float yi = y[b * NDIM + t];
    f32x2 r2[32];
    build_rows(r2, ws, xi, yi, t);

    float colreg = r2[0].x;
    float dval = (t == 0) ? r2[0].x : 0.0f;
    float e2val = 0.0f;
    tri_chunk< 0,  8>(r2, colreg, dval, e2val, t);
    tri_chunk< 8, 16>(r2, colreg, dval, e2val, t);
    tri_chunk<16, 24>(r2, colreg, dval, e2val, t);
    tri_chunk<24, 32>(r2, colreg, dval, e2val, t);
    tri_chunk<32, 40>(r2, colreg, dval, e2val, t);
    tri_chunk<40, 48>(r2, colreg, dval, e2val, t);
    tri_chunk<48, 56>(r2, colreg, dval, e2val, t);
    tri_chunk<56, 62>(r2, colreg, dval, e2val, t);

    float e62 = rl(colreg, 63);
    e2val = (t == 62) ? e62 * e62 : e2val;
    dval = (t == 63) ? r2[31].y : dval;

    sturm_out<NDIM>(dval, e2val, idx, t, b, out);
}

extern "C" void kernel_launch(void* const* d_in, const int* in_sizes, int n_in,
                              void* d_out, int out_size, void* d_ws, size_t ws_size,
                              hipStream_t stream) {
    const float* x = (const float*)d_in[0];
    const float* y = (const float*)d_in[1];
    const float* A = (const float*)d_in[2];
    const float* B = (const float*)d_in[3];
    const float* C = (const float*)d_in[4];
    const int* idxp = (const int*)d_in[5];
    float* out = (float*)d_out;
    float* ws = (float*)d_ws;
    int batch = in_sizes[0] / NDIM;

    hipLaunchKernelGGL(prep_kernel, dim3(1), dim3(64), 0, stream, A, B, C, ws);
    hipLaunchKernelGGL(lanczos_kernel, dim3((batch + 3) / 4), dim3(256), 0, stream,
                       x, y, ws, idxp, out, batch);
    hipLaunchKernelGGL(householder_kernel, dim3((batch + 3) / 4), dim3(256), 0, stream,
                       x, y, ws, idxp, out, batch);
}

// Round 19
// 324.395 us; speedup vs baseline: 1.7792x; 1.1699x over previous
//
#include <hip/hip_runtime.h>
#include <math.h>

#define NDIM 64
#define KSTEPS 32
typedef float f32x2 __attribute__((ext_vector_type(2)));

#define MEMFENCE() asm volatile("" ::: "memory")

// Broadcast lane `lane`'s value to all lanes (uniform / SGPR).
__device__ __forceinline__ float rl(float v, int lane) {
    return __uint_as_float((unsigned)__builtin_amdgcn_readlane(__float_as_uint(v), lane));
}

// DPP add step with compile-time control/row mask.
template<int CTRL, int ROW_MASK>
__device__ __forceinline__ float dpp_add(float x) {
    int m = __builtin_amdgcn_update_dpp(0, __float_as_int(x), CTRL, ROW_MASK, 0xf, true);
    return x + __int_as_float(m);
}
// Full-wave64 sum via DPP; total lands in lane 63, broadcast via readlane.
__device__ __forceinline__ float wave_sum(float x) {
    x = dpp_add<0x111, 0xf>(x);   // row_shr:1
    x = dpp_add<0x112, 0xf>(x);   // row_shr:2
    x = dpp_add<0x114, 0xf>(x);   // row_shr:4
    x = dpp_add<0x118, 0xf>(x);   // row_shr:8
    x = dpp_add<0x142, 0xa>(x);   // row_bcast:15 -> rows 1,3
    x = dpp_add<0x143, 0xc>(x);   // row_bcast:31 -> row 3
    return rl(x, 63);
}
__device__ __forceinline__ float wave_min(float v) {
    #pragma unroll
    for (int off = 1; off < 64; off <<= 1) v = fminf(v, __shfl_xor(v, off, 64));
    return v;
}
__device__ __forceinline__ float wave_max(float v) {
    #pragma unroll
    for (int off = 1; off < 64; off <<= 1) v = fmaxf(v, __shfl_xor(v, off, 64));
    return v;
}

// Build symmetrized row t into r2 (32 x f32x2) using readlane broadcasts.
__device__ __forceinline__ void build_rows(f32x2 (&r2)[32], const float* ws,
                                           float xi, float yi, int t) {
    const float4* Sa4 = (const float4*)(ws + t * NDIM);
    const float4* Bh4 = (const float4*)(ws + 4096 + t * NDIM);
    const float4* Bt4 = (const float4*)(ws + 8192 + t * NDIM);
    const float4* Ch4 = (const float4*)(ws + 12288 + t * NDIM);
    const float4* Ct4 = (const float4*)(ws + 16384 + t * NDIM);
    #pragma unroll
    for (int q = 0; q < 16; ++q) {
        float4 sa = Sa4[q], bh = Bh4[q], bt = Bt4[q], ch = Ch4[q], ct = Ct4[q];
        float x0 = rl(xi, 4 * q),     y0 = rl(yi, 4 * q);
        float x1 = rl(xi, 4 * q + 1), y1 = rl(yi, 4 * q + 1);
        float x2 = rl(xi, 4 * q + 2), y2 = rl(yi, 4 * q + 2);
        float x3 = rl(xi, 4 * q + 3), y3 = rl(yi, 4 * q + 3);
        float e0 = fmaf(bh.x, x0, fmaf(bt.x, xi, fmaf(ch.x, y0, fmaf(ct.x, yi, sa.x))));
        float e1 = fmaf(bh.y, x1, fmaf(bt.y, xi, fmaf(ch.y, y1, fmaf(ct.y, yi, sa.y))));
        float e2 = fmaf(bh.z, x2, fmaf(bt.z, xi, fmaf(ch.z, y2, fmaf(ct.z, yi, sa.z))));
        float e3 = fmaf(bh.w, x3, fmaf(bt.w, xi, fmaf(ch.w, y3, fmaf(ct.w, yi, sa.w))));
        r2[2 * q].x = e0;     r2[2 * q].y = e1;
        r2[2 * q + 1].x = e2; r2[2 * q + 1].y = e3;
    }
}

// Shared tail: Gershgorin bounds over lanes < NACT + 64-way Sturm multisection
// (register/readlane form; recurrence length NACT at compile time).
template<int NACT>
__device__ __forceinline__ void sturm_out(float dval, float e2val, int idx,
                                          int t, int b, float* out) {
    bool act = (t < NACT);
    float eabs = sqrtf(e2val);
    float eprev = __shfl_up(eabs, 1, 64);
    eprev = (t == 0) ? 0.0f : eprev;
    float rad = eabs + eprev;
    float lo = wave_min(act ? dval - rad : 1e30f);
    float hi = wave_max(act ? dval + rad : -1e30f);
    float pad = 1e-3f + 1e-5f * fmaxf(fabsf(lo), fabsf(hi));
    lo -= pad;
    hi += pad;

    #pragma unroll 1
    for (int it = 0; it < 2; ++it) {
        float wdt = (hi - lo) * (1.0f / 65.0f);
        float s = lo + wdt * (float)(t + 1);
        float q = rl(dval, 0) - s;
        q = (fabsf(q) < 1e-12f) ? -1e-12f : q;
        int cnt = (q < 0.0f) ? 1 : 0;
        #pragma unroll
        for (int i = 1; i < NACT; ++i) {
            q = rl(dval, i) - s - rl(e2val, i - 1) * __builtin_amdgcn_rcpf(q);
            q = (fabsf(q) < 1e-12f) ? -1e-12f : q;
            cnt += (q < 0.0f) ? 1 : 0;
        }
        unsigned long long m = __ballot(cnt <= idx);
        int p = (int)__popcll(m);
        float nlo = lo + wdt * (float)p;
        float nhi = lo + wdt * (float)(p + 1);
        lo = nlo;
        hi = (p >= 64) ? hi : nhi;
    }
    if (t == 0) out[b] = 0.5f * (lo + hi);
}

// One-time prep: Sa = 0.5(A+A^T), Bh = 0.5B, Bt = 0.5B^T, Ch = 0.5C, Ct = 0.5C^T.
__global__ __launch_bounds__(64)
void prep_kernel(const float* __restrict__ A, const float* __restrict__ B,
                 const float* __restrict__ C, float* __restrict__ ws) {
    const int t = threadIdx.x;
    float* Sa = ws;
    float* Bh = ws + 4096;
    float* Bt = ws + 8192;
    float* Ch = ws + 12288;
    float* Ct = ws + 16384;
    for (int j = 0; j < NDIM; ++j) {
        Sa[t * NDIM + j] = 0.5f * (A[t * NDIM + j] + A[j * NDIM + t]);
        Bh[t * NDIM + j] = 0.5f * B[t * NDIM + j];
        Bt[t * NDIM + j] = 0.5f * B[j * NDIM + t];
        Ch[t * NDIM + j] = 0.5f * C[t * NDIM + j];
        Ct[t * NDIM + j] = 0.5f * C[j * NDIM + t];
    }
}

// ===== Truncated Lanczos (K=32), extreme indices (idx==0 or idx==63).
// Kaniel-Paige: extremal Ritz error ~ range*exp(-4K*sqrt(gamma)); at K=32
// even 10x-smaller-than-typical edge gaps give error ~0.04 << 0.6175.
// q-buffer typed f32x2: ds_read results feed v_pk_fma directly.
// Sturm on the K-dim T only (idx==63 -> T's largest, idx_eff=K-1).
__global__ __launch_bounds__(256, 4)
void lanczos_kernel(const float* __restrict__ x, const float* __restrict__ y,
                    const float* __restrict__ ws, const int* __restrict__ idxp,
                    float* __restrict__ out, int batch) {
    int idx = idxp[0];
    idx = idx < 0 ? 0 : (idx > NDIM - 1 ? NDIM - 1 : idx);
    if (idx != 0 && idx != NDIM - 1) return;   // interior: householder kernel
    const int idx_eff = (idx == 0) ? 0 : (KSTEPS - 1);

    const int t = threadIdx.x & 63;
    const int wv = threadIdx.x >> 6;
    const int b = blockIdx.x * 4 + wv;
    if (b >= batch) return;

    __shared__ f32x2 qbs[4][64];
    f32x2* qb2 = qbs[wv];
    float* qbp = (float*)qb2;

    const float xi = x[b * NDIM + t];
    const float yi = y[b * NDIM + t];
    f32x2 r2[32];
    build_rows(r2, ws, xi, yi, t);

    // Lanczos: q0 = e_0. T diag alpha_k -> lane k, offdiag beta_{k+1}^2 -> lane k.
    float q = (t == 0) ? 1.0f : 0.0f;
    qbp[t] = q;
    MEMFENCE();
    float qp = 0.0f, bprev = 0.0f;
    float dval = 0.0f, e2val = 0.0f;
    #pragma unroll 1
    for (int k = 0; k < KSTEPS - 1; ++k) {
        // matvec: 4 independent 8-deep pk-FMA chains; operands direct from LDS
        f32x2 a0 = {0.0f, 0.0f}, a1 = {0.0f, 0.0f};
        f32x2 a2 = {0.0f, 0.0f}, a3 = {0.0f, 0.0f};
        #pragma unroll
        for (int m = 0; m < 32; m += 4) {
            a0 = __builtin_elementwise_fma(r2[m],     qb2[m],     a0);
            a1 = __builtin_elementwise_fma(r2[m + 1], qb2[m + 1], a1);
            a2 = __builtin_elementwise_fma(r2[m + 2], qb2[m + 2], a2);
            a3 = __builtin_elementwise_fma(r2[m + 3], qb2[m + 3], a3);
        }
        f32x2 st = (a0 + a1) + (a2 + a3);
        float w = st.x + st.y;
        w = fmaf(-bprev, qp, w);
        // merged independent reductions
        float alpha = wave_sum(q * w);
        float sww = wave_sum(w * w);
        float b2 = fmaxf(fmaf(-alpha, alpha, sww), 0.0f);
        float binv = (b2 > 1e-20f) ? rsqrtf(b2) : 0.0f;
        float wn = fmaf(-alpha, q, w);
        qp = q;
        q = wn * binv;
        qbp[t] = q;                       // publish next q ASAP
        MEMFENCE();
        // shadow work (under the write->read gap)
        bool cap = (t == k);
        dval = cap ? alpha : dval;
        e2val = cap ? b2 : e2val;         // beta_{k+1}^2
        bprev = b2 * binv;                // sqrt(b2)
    }
    // peeled last step (k = KSTEPS-1): only alpha needed
    {
        f32x2 a0 = {0.0f, 0.0f}, a1 = {0.0f, 0.0f};
        f32x2 a2 = {0.0f, 0.0f}, a3 = {0.0f, 0.0f};
        #pragma unroll
        for (int m = 0; m < 32; m += 4) {
            a0 = __builtin_elementwise_fma(r2[m],     qb2[m],     a0);
            a1 = __builtin_elementwise_fma(r2[m + 1], qb2[m + 1], a1);
            a2 = __builtin_elementwise_fma(r2[m + 2], qb2[m + 2], a2);
            a3 = __builtin_elementwise_fma(r2[m + 3], qb2[m + 3], a3);
        }
        f32x2 st = (a0 + a1) + (a2 + a3);
        float w = st.x + st.y;
        w = fmaf(-bprev, qp, w);
        float alpha = wave_sum(q * w);
        dval = (t == KSTEPS - 1) ? alpha : dval;
        // lane KSTEPS-1 e2val stays 0 -> truncated T decoupled
    }

    sturm_out<KSTEPS>(dval, e2val, idx_eff, t, b, out);
}

// ===== Householder path: interior indices (exact-count Sturm needs a
// ghost-free tridiagonal). Verified R12 structure. =====
template<int K0, int K1>
__device__ __forceinline__ void tri_chunk(f32x2 (&r2)[32], float& colreg,
                                          float& dval, float& e2val, const int t) {
    #pragma unroll 1
    for (int k = K0; k < K1; ++k) {
        float akt = (t > k) ? colreg : 0.0f;
        float s2 = wave_sum(akt * akt);
        float a1 = rl(akt, k + 1);
        float sigma = sqrtf(s2);
        float alpha = (a1 >= 0.0f) ? -sigma : sigma;
        e2val = (t == k) ? s2 : e2val;
        float vt = akt - ((t == k + 1) ? alpha : 0.0f);
        float vtv = 2.0f * (s2 - alpha * a1);
        float beta = (vtv > 1e-30f) ? 2.0f * __builtin_amdgcn_rcpf(vtv) : 0.0f;

        float pre_col = colreg;
        #pragma unroll
        for (int j = K0 + 1; j <= K1; ++j)
            if (j == k + 1) pre_col = (j & 1) ? r2[j >> 1].y : r2[j >> 1].x;

        f32x2 acc0 = {0.0f, 0.0f}, acc1 = {0.0f, 0.0f};
        #pragma unroll
        for (int p = K0 / 2; p < 32; ++p) {
            f32x2 a;
            a.x = rl(akt, 2 * p);
            a.y = rl(akt, 2 * p + 1);
            if (p & 1) acc1 = __builtin_elementwise_fma(r2[p], a, acc1);
            else       acc0 = __builtin_elementwise_fma(r2[p], a, acc0);
        }
        float ut = (acc0.x + acc0.y) + (acc1.x + acc1.y) - alpha * pre_col;
        float vtu = wave_sum(vt * ut);
        float c  = 0.5f * beta * beta * vtu;
        float p1 = vt * beta;
        float p2 = (t > k) ? (beta * ut - 2.0f * c * vt) : 0.0f;
        float uk1 = rl(ut, k + 1);
        float ncol = pre_col - p1 * uk1 - p2 * a1 + alpha * p2;

        f32x2 np1; np1.x = -p1; np1.y = -p1;
        f32x2 np2; np2.x = -p2; np2.y = -p2;
        #pragma unroll
        for (int p = K0 / 2; p < 32; ++p) {
            f32x2 u, a;
            u.x = rl(ut, 2 * p);
            u.y = rl(ut, 2 * p + 1);
            a.x = rl(akt, 2 * p);
            a.y = rl(akt, 2 * p + 1);
            r2[p] = __builtin_elementwise_fma(np1, u,
                    __builtin_elementwise_fma(np2, a, r2[p]));
        }
        #pragma unroll
        for (int j = K0 + 1; j <= K1; ++j) {
            if (j == k + 1) {
                if (j & 1) r2[j >> 1].y = ncol; else r2[j >> 1].x = ncol;
            }
        }
        colreg = ncol;
        dval = (t == k + 1) ? ncol : dval;
    }
}

__global__ __launch_bounds__(256, 1)
void householder_kernel(const float* __restrict__ x, const float* __restrict__ y,
                        const float* __restrict__ ws, const int* __restrict__ idxp,
                        float* __restrict__ out, int batch) {
    int idx = idxp[0];
    idx = idx < 0 ? 0 : (idx > NDIM - 1 ? NDIM - 1 : idx);
    if (idx == 0 || idx == NDIM - 1) return;   // handled by lanczos kernel

    const int t = threadIdx.x & 63;
    const int b = blockIdx.x * 4 + (threadIdx.x >> 6);
    if (b >= batch) return;

    const float xi = x[b * NDIM + t];
    const float yi = y[b * NDIM + t];
    f32x2 r2[32];
    build_rows(r2, ws, xi, yi, t);

    float colreg = r2[0].x;
    float dval = (t == 0) ? r2[0].x : 0.0f;
    float e2val = 0.0f;
    tri_chunk< 0,  8>(r2, colreg, dval, e2val, t);
    tri_chunk< 8, 16>(r2, colreg, dval, e2val, t);
    tri_chunk<16, 24>(r2, colreg, dval, e2val, t);
    tri_chunk<24, 32>(r2, colreg, dval, e2val, t);
    tri_chunk<32, 40>(r2, colreg, dval, e2val, t);
    tri_chunk<40, 48>(r2, colreg, dval, e2val, t);
    tri_chunk<48, 56>(r2, colreg, dval, e2val, t);
    tri_chunk<56, 62>(r2, colreg, dval, e2val, t);

    float e62 = rl(colreg, 63);
    e2val = (t == 62) ? e62 * e62 : e2val;
    dval = (t == 63) ? r2[31].y : dval;

    sturm_out<NDIM>(dval, e2val, idx, t, b, out);
}

extern "C" void kernel_launch(void* const* d_in, const int* in_sizes, int n_in,
                              void* d_out, int out_size, void* d_ws, size_t ws_size,
                              hipStream_t stream) {
    const float* x = (const float*)d_in[0];
    const float* y = (const float*)d_in[1];
    const float* A = (const float*)d_in[2];
    const float* B = (const float*)d_in[3];
    const float* C = (const float*)d_in[4];
    const int* idxp = (const int*)d_in[5];
    float* out = (float*)d_out;
    float* ws = (float*)d_ws;
    int batch = in_sizes[0] / NDIM;

    hipLaunchKernelGGL(prep_kernel, dim3(1), dim3(64), 0, stream, A, B, C, ws);
    hipLaunchKernelGGL(lanczos_kernel, dim3((batch + 3) / 4), dim3(256), 0, stream,
                       x, y, ws, idxp, out, batch);
    hipLaunchKernelGGL(householder_kernel, dim3((batch + 3) / 4), dim3(256), 0, stream,
                       x, y, ws, idxp, out, batch);
}